// Round 16
// baseline (609.226 us; speedup 1.0000x reference)
//
#include <hip/hip_runtime.h>
#include <hip/hip_bf16.h>
#include <math.h>

#define HH 16
#define SS 2048
#define BBATCH 2
#define NROWS 4096   // B*S

typedef __attribute__((ext_vector_type(8))) __bf16 bf16x8;
typedef __attribute__((ext_vector_type(4))) float f32x4;
typedef const __attribute__((address_space(1))) unsigned int* gas1_t;
typedef __attribute__((address_space(3))) unsigned int* las3_t;

__device__ __forceinline__ unsigned short f2bf(float f) {
  unsigned u = __builtin_bit_cast(unsigned, f);
  u += 0x7fffu + ((u >> 16) & 1u);
  return (unsigned short)(u >> 16);
}
__device__ __forceinline__ float bf2f(unsigned short u) {
  return __builtin_bit_cast(float, (unsigned)u << 16);
}

__device__ __forceinline__ void gload16(const void* g, void* l) {
  __builtin_amdgcn_global_load_lds((gas1_t)g, (las3_t)l, 16, 0, 0);
}
__device__ __forceinline__ f32x4 mfma16(bf16x8 a, bf16x8 b, f32x4 c) {
  return __builtin_amdgcn_mfma_f32_16x16x32_bf16(a, b, c, 0, 0, 0);
}

// ---------------- transpose body: W (K,N) f32 -> Wt (Npad,K) bf16 ----------------
__device__ __forceinline__ void transpose_body(const float* __restrict__ W,
                                               unsigned short* __restrict__ Wt,
                                               int K, int N, int Npad,
                                               int bx, int by, float (*tile)[33], int tid) {
  int n0 = bx * 32, k0 = by * 32;
  int tx = tid & 31, ty = tid >> 5;
  for (int i = ty; i < 32; i += 8) {
    int k = k0 + i, n = n0 + tx;
    tile[i][tx] = (k < K && n < N) ? W[(long)k * N + n] : 0.f;
  }
  __syncthreads();
  for (int i = ty; i < 32; i += 8) {
    int n = n0 + i, k = k0 + tx;
    if (n < Npad && k < K) Wt[(long)n * K + k] = f2bf(tile[tx][i]);
  }
}

// ---------------- fused preprocessing: convert + 5 transposes + bias + rope table ----------------
__global__ __launch_bounds__(256) void k_prep(const float* __restrict__ x,
                                              unsigned short* __restrict__ xb,
                                              const float* __restrict__ wqd,
                                              const float* __restrict__ wqu,
                                              const float* __restrict__ wkvd,
                                              const float* __restrict__ wkvu,
                                              const float* __restrict__ wout,
                                              unsigned short* __restrict__ wqkt,
                                              unsigned short* __restrict__ wqut,
                                              unsigned short* __restrict__ wkvut,
                                              unsigned short* __restrict__ woutt,
                                              const float* __restrict__ bqd,
                                              const float* __restrict__ bkvd,
                                              float* __restrict__ mbias,
                                              float2* __restrict__ rtab) {
  __shared__ float tile[32][33];
  int blk = blockIdx.x;
  int tid = threadIdx.x;
  if (blk < 2048) {
    long n4 = (long)NROWS * 2048 / 4;
    for (long i = (long)blk * 256 + tid; i < n4; i += 2048 * 256) {
      float4 v = ((const float4*)x)[i];
      ushort4 o = { f2bf(v.x), f2bf(v.y), f2bf(v.z), f2bf(v.w) };
      ((ushort4*)xb)[i] = o;
    }
  } else if (blk < 5120) {
    int t = blk - 2048;
    transpose_body(wqd, wqkt, 2048, 1536, 1536, t % 48, t / 48, tile, tid);
  } else if (blk < 9728) {
    int t = blk - 5120;
    transpose_body(wqu, wqut, 1536, 3072, 3072, t % 96, t / 96, tile, tid);
  } else if (blk < 11008) {
    int t = blk - 9728;
    transpose_body(wkvd, wqkt + (size_t)1536 * 2048, 2048, 576, 640, t % 20, t / 20, tile, tid);
  } else if (blk < 13056) {
    int t = blk - 11008;
    transpose_body(wkvu, wkvut, 512, 4096, 4096, t % 128, t / 128, tile, tid);
  } else if (blk < 17152) {
    int t = blk - 13056;
    transpose_body(wout, woutt, 2048, 2048, 2048, t % 64, t / 64, tile, tid);
  } else if (blk < 17161) {
    int i = (blk - 17152) * 256 + tid;
    if (i < 2176) mbias[i] = i < 1536 ? bqd[i] : (i < 2112 ? bkvd[i - 1536] : 0.f);
  } else {
    int t = blk - 17161;                    // 256 blocks, 8 s each
    int s = t * 8 + (tid >> 5);
    int i = tid & 31;
    float inv = powf(10000.f, -(float)i / 32.f);
    float ang = (float)s * inv;
    float sn, cs;
    sincosf(ang, &sn, &cs);
    rtab[s * 32 + i] = make_float2(cs, sn);
  }
}

// ---------------- GEMM: C(M,N) f32 = A(M,K)bf16 * Bt(Npad,K)bf16 + bias ----------------
__global__ __launch_bounds__(256) void k_gemm(const unsigned short* __restrict__ A,
                                              const unsigned short* __restrict__ Bt,
                                              const float* __restrict__ bias,
                                              float* __restrict__ C,
                                              int M, int N, int K) {
  __shared__ unsigned short lA[128 * 32];
  __shared__ unsigned short lB[128 * 32];
  int tid = threadIdx.x;
  int wave = tid >> 6, lane = tid & 63;
  int l15 = lane & 15, lhi = lane >> 4;
  int ntn = (N + 127) >> 7;
  int tm = blockIdx.x / ntn, tn = blockIdx.x % ntn;
  long row0 = (long)tm * 128, col0 = (long)tn * 128;
  int wr = wave >> 1, wc = wave & 1;

  const unsigned short* gA = A + (row0 + (tid >> 2)) * K + (tid & 3) * 8;
  const unsigned short* gB = Bt + (col0 + (tid >> 2)) * K + (tid & 3) * 8;
  unsigned short* lA0 = &lA[tid * 8];
  unsigned short* lB0 = &lB[tid * 8];

  f32x4 acc[4][4] = {};
  for (int k0 = 0; k0 < K; k0 += 32) {
    __syncthreads();
    gload16(gA + k0, lA0);
    gload16(gA + (long)64 * K + k0, lA0 + 2048);
    gload16(gB + k0, lB0);
    gload16(gB + (long)64 * K + k0, lB0 + 2048);
    asm volatile("s_waitcnt vmcnt(0)" ::: "memory");
    __syncthreads();
    bf16x8 af[4], bfr[4];
#pragma unroll
    for (int i = 0; i < 4; ++i) {
      af[i]  = *(const bf16x8*)&lA[(wr * 64 + i * 16 + l15) * 32 + lhi * 8];
      bfr[i] = *(const bf16x8*)&lB[(wc * 64 + i * 16 + l15) * 32 + lhi * 8];
    }
#pragma unroll
    for (int i = 0; i < 4; ++i)
#pragma unroll
      for (int j = 0; j < 4; ++j)
        acc[i][j] = mfma16(af[i], bfr[j], acc[i][j]);
  }
#pragma unroll
  for (int i = 0; i < 4; ++i)
#pragma unroll
    for (int j = 0; j < 4; ++j) {
      long r = row0 + wr * 64 + i * 16 + lhi * 4;
      long c = col0 + wc * 64 + j * 16 + l15;
      if (c < N) {
        float bv = bias[c];
#pragma unroll
        for (int rr = 0; rr < 4; ++rr)
          C[(r + rr) * N + c] = acc[i][j][rr] + bv;
      }
    }
}

// ---------------- GEMM with bf16 output (down-proj -> sC bf16) ----------------
__global__ __launch_bounds__(256) void k_gemm_c16(const unsigned short* __restrict__ A,
                                                  const unsigned short* __restrict__ Bt,
                                                  const float* __restrict__ bias,
                                                  unsigned short* __restrict__ C,
                                                  int M, int N, int K) {
  __shared__ unsigned short lA[128 * 32];
  __shared__ unsigned short lB[128 * 32];
  int tid = threadIdx.x;
  int wave = tid >> 6, lane = tid & 63;
  int l15 = lane & 15, lhi = lane >> 4;
  int ntn = (N + 127) >> 7;
  int tm = blockIdx.x / ntn, tn = blockIdx.x % ntn;
  long row0 = (long)tm * 128, col0 = (long)tn * 128;
  int wr = wave >> 1, wc = wave & 1;

  const unsigned short* gA = A + (row0 + (tid >> 2)) * K + (tid & 3) * 8;
  const unsigned short* gB = Bt + (col0 + (tid >> 2)) * K + (tid & 3) * 8;
  unsigned short* lA0 = &lA[tid * 8];
  unsigned short* lB0 = &lB[tid * 8];

  f32x4 acc[4][4] = {};
  for (int k0 = 0; k0 < K; k0 += 32) {
    __syncthreads();
    gload16(gA + k0, lA0);
    gload16(gA + (long)64 * K + k0, lA0 + 2048);
    gload16(gB + k0, lB0);
    gload16(gB + (long)64 * K + k0, lB0 + 2048);
    asm volatile("s_waitcnt vmcnt(0)" ::: "memory");
    __syncthreads();
    bf16x8 af[4], bfr[4];
#pragma unroll
    for (int i = 0; i < 4; ++i) {
      af[i]  = *(const bf16x8*)&lA[(wr * 64 + i * 16 + l15) * 32 + lhi * 8];
      bfr[i] = *(const bf16x8*)&lB[(wc * 64 + i * 16 + l15) * 32 + lhi * 8];
    }
#pragma unroll
    for (int i = 0; i < 4; ++i)
#pragma unroll
      for (int j = 0; j < 4; ++j)
        acc[i][j] = mfma16(af[i], bfr[j], acc[i][j]);
  }
#pragma unroll
  for (int i = 0; i < 4; ++i)
#pragma unroll
    for (int j = 0; j < 4; ++j) {
      long r = row0 + wr * 64 + i * 16 + lhi * 4;
      long c = col0 + wc * 64 + j * 16 + l15;
      if (c < N) {
        float bv = bias[c];
#pragma unroll
        for (int rr = 0; rr < 4; ++rr)
          C[(r + rr) * N + c] = f2bf(acc[i][j][rr] + bv);
      }
    }
}

// ---------------- merged up-projections + krope in ONE launch ----------------
// blocks [0,768): qf GEMM (N=3072, K=1536, fused rope/scale epilogue)
// blocks [768,1792): kv GEMM (N=4096, K=512, fused kf3/vt3 tiled epilogue)
// blocks [1792,2816): krope (4 rows/block, table-based)
__global__ __launch_bounds__(256) void k_up(const unsigned short* __restrict__ qn,
                                            const unsigned short* __restrict__ wqut,
                                            const float* __restrict__ bqu,
                                            const unsigned short* __restrict__ kvn,
                                            const unsigned short* __restrict__ wkvut,
                                            const float* __restrict__ bkvu,
                                            const unsigned short* __restrict__ sCb,
                                            const float2* __restrict__ rtab,
                                            unsigned short* __restrict__ qf,
                                            unsigned short* __restrict__ kf3,
                                            unsigned short* __restrict__ vt3) {
  __shared__ unsigned short smem[16384];   // 32KB
  unsigned short* lA = smem;
  unsigned short* lB = smem + 4096;
  int blk = blockIdx.x;
  int tid = threadIdx.x;
  int wave = tid >> 6, lane = tid & 63;
  int l15 = lane & 15, lhi = lane >> 4;
  int wr = wave >> 1, wc = wave & 1;

  if (blk < 768) {
    // ---- qf GEMM ----
    const int N = 3072, K = 1536;
    int tm = blk / 24, tn = blk % 24;
    long row0 = (long)tm * 128, col0 = (long)tn * 128;
    const unsigned short* gA = qn + (row0 + (tid >> 2)) * K + (tid & 3) * 8;
    const unsigned short* gB = wqut + (col0 + (tid >> 2)) * K + (tid & 3) * 8;
    unsigned short* lA0 = &lA[tid * 8];
    unsigned short* lB0 = &lB[tid * 8];
    f32x4 acc[4][4] = {};
    for (int k0 = 0; k0 < K; k0 += 32) {
      __syncthreads();
      gload16(gA + k0, lA0);
      gload16(gA + (long)64 * K + k0, lA0 + 2048);
      gload16(gB + k0, lB0);
      gload16(gB + (long)64 * K + k0, lB0 + 2048);
      asm volatile("s_waitcnt vmcnt(0)" ::: "memory");
      __syncthreads();
      bf16x8 af[4], bfr[4];
#pragma unroll
      for (int i = 0; i < 4; ++i) {
        af[i]  = *(const bf16x8*)&lA[(wr * 64 + i * 16 + l15) * 32 + lhi * 8];
        bfr[i] = *(const bf16x8*)&lB[(wc * 64 + i * 16 + l15) * 32 + lhi * 8];
      }
#pragma unroll
      for (int i = 0; i < 4; ++i)
#pragma unroll
        for (int j = 0; j < 4; ++j)
          acc[i][j] = mfma16(af[i], bfr[j], acc[i][j]);
    }
    const float scq = 0.07216878364870322f * 1.4426950408889634f;  // 192^-0.5 * log2(e)
    int base = (int)col0 + wc * 64;
    int h = base / 192;
    int m192 = base - h * 192;   // 0, 64, or 128 (wave-uniform)
    float bv[4];
#pragma unroll
    for (int j = 0; j < 4; ++j) bv[j] = bqu[base + j * 16 + l15];
#pragma unroll
    for (int i = 0; i < 4; ++i) {
#pragma unroll
      for (int rr = 0; rr < 4; ++rr) {
        long r = row0 + wr * 64 + i * 16 + lhi * 4 + rr;
        int s = (int)(r & 2047), b = (int)(r >> 11);
        unsigned short* dst = qf + (((long)(b * HH + h)) * SS + s) * 192;
        if (m192 < 128) {
#pragma unroll
          for (int j = 0; j < 4; ++j)
            dst[m192 + j * 16 + l15] = f2bf((acc[i][j][rr] + bv[j]) * scq);
        } else {
#pragma unroll
          for (int j = 0; j < 2; ++j) {
            int ifq = j * 16 + l15;
            float2 cs = rtab[s * 32 + ifq];
            float v1 = acc[i][j][rr] + bv[j];
            float v2 = acc[i][j + 2][rr] + bv[j + 2];
            dst[128 + ifq] = f2bf((v1 * cs.x - v2 * cs.y) * scq);
            dst[160 + ifq] = f2bf((v2 * cs.x + v1 * cs.y) * scq);
          }
        }
      }
    }
  } else if (blk < 1792) {
    // ---- kv GEMM with tiled epilogue ----
    const int N = 4096, K = 512;
    int b2 = blk - 768;
    int tm = b2 / 32, tn = b2 % 32;
    long row0 = (long)tm * 128, col0 = (long)tn * 128;
    const unsigned short* gA = kvn + (row0 + (tid >> 2)) * K + (tid & 3) * 8;
    const unsigned short* gB = wkvut + (col0 + (tid >> 2)) * K + (tid & 3) * 8;
    unsigned short* lA0 = &lA[tid * 8];
    unsigned short* lB0 = &lB[tid * 8];
    f32x4 acc[4][4] = {};
    for (int k0 = 0; k0 < K; k0 += 32) {
      __syncthreads();
      gload16(gA + k0, lA0);
      gload16(gA + (long)64 * K + k0, lA0 + 2048);
      gload16(gB + k0, lB0);
      gload16(gB + (long)64 * K + k0, lB0 + 2048);
      asm volatile("s_waitcnt vmcnt(0)" ::: "memory");
      __syncthreads();
      bf16x8 af[4], bfr[4];
#pragma unroll
      for (int i = 0; i < 4; ++i) {
        af[i]  = *(const bf16x8*)&lA[(wr * 64 + i * 16 + l15) * 32 + lhi * 8];
        bfr[i] = *(const bf16x8*)&lB[(wc * 64 + i * 16 + l15) * 32 + lhi * 8];
      }
#pragma unroll
      for (int i = 0; i < 4; ++i)
#pragma unroll
        for (int j = 0; j < 4; ++j)
          acc[i][j] = mfma16(af[i], bfr[j], acc[i][j]);
    }
    int base = (int)col0 + wc * 64;
    int h = base >> 8;
    bool isv = (base & 255) >= 128;   // block-uniform (tn parity)
    float bv[4];
#pragma unroll
    for (int j = 0; j < 4; ++j) bv[j] = bkvu[base + j * 16 + l15];
    int b = (int)(row0 >> 11);
    long bh = (long)b * HH + h;
    int lrb = wr * 64;
    __syncthreads();
    if (isv) {
#pragma unroll
      for (int i = 0; i < 4; ++i) {
        int lr = lrb + i * 16 + lhi * 4;
#pragma unroll
        for (int j = 0; j < 4; ++j) {
          int lc = wc * 64 + j * 16 + l15;
          ushort4 pk = { f2bf(acc[i][j][0] + bv[j]), f2bf(acc[i][j][1] + bv[j]),
                         f2bf(acc[i][j][2] + bv[j]), f2bf(acc[i][j][3] + bv[j]) };
          *(ushort4*)&smem[((lr >> 5) << 12) + lc * 32 + (lr & 31)] = pk;
        }
      }
      __syncthreads();
      long dst0 = (bh * 64 + ((row0 & 2047) >> 5)) * 4096;
#pragma unroll
      for (int p = 0; p < 8; ++p) {
        int e = p * 256 + tid;
        *(uint4*)&vt3[dst0 + e * 8] = *(uint4*)&smem[e * 8];
      }
    } else {
#pragma unroll
      for (int i = 0; i < 4; ++i) {
        int lr0 = lrb + i * 16 + lhi * 4;
#pragma unroll
        for (int j = 0; j < 4; ++j) {
          int c = (base & 255) + j * 16 + l15;   // 0..127
          int tbase = ((lr0 >> 4) << 11) + ((c >> 5) << 9) + (((c >> 3) & 3) << 7) + (c & 7);
#pragma unroll
          for (int rr = 0; rr < 4; ++rr)
            smem[tbase + ((lr0 + rr) & 15) * 8] = f2bf(acc[i][j][rr] + bv[j]);
        }
      }
      __syncthreads();
      long kb3 = (bh * 128 + ((row0 & 2047) >> 4)) * 3072;
#pragma unroll
      for (int p = 0; p < 8; ++p) {
        int e = p * 256 + tid;
        int tile = e >> 6;
        int off = (e & 63) * 8;
        long dst = kb3 + ((long)(tile >> 2) * 6 + (tile & 3)) * 512 + off;
        *(uint4*)&kf3[dst] = *(uint4*)&smem[tile * 512 + off];
      }
    }
  } else {
    // ---- krope: 4 rows per block ----
    int t = blk - 1792;
    int bs = t * 4 + (tid >> 6);
    int s = bs & (SS - 1), b = bs >> 11;
    const unsigned short* src = sCb + (long)bs * 2176 + 2048;
    int i = lane & 31;
    float2 cs = rtab[s * 32 + i];
    float t1 = bf2f(src[i]), t2 = bf2f(src[32 + i]);
    float v = (lane < 32) ? (t1 * cs.x - t2 * cs.y) : (t2 * cs.x + t1 * cs.y);
    unsigned short bv = f2bf(v);
    int d = 128 + lane;
    long inner = (long)(d >> 5) * 512 + ((d >> 3) & 3) * 128 + (s & 15) * 8 + (d & 7);
#pragma unroll
    for (int h = 0; h < HH; ++h) {
      long kblk = ((long)(b * HH + h) * 128 + (s >> 4)) * 6;
      kf3[kblk * 512 + inner] = bv;
    }
  }
}

// ---------------- merged RMSNorm (q rows then kv rows): bf16 -> bf16 ----------------
__global__ __launch_bounds__(256) void k_rmsnorm2(const unsigned short* __restrict__ sC,
                                                  const float* __restrict__ qnw,
                                                  const float* __restrict__ kvnw,
                                                  unsigned short* __restrict__ qn,
                                                  unsigned short* __restrict__ kvn) {
  int blk = blockIdx.x;
  long row;
  const unsigned short* x;
  const float* w;
  unsigned short* y;
  int L;
  if (blk < NROWS) {
    row = blk; x = sC + row * 2176; w = qnw; y = qn + row * 1536; L = 1536;
  } else {
    row = blk - NROWS; x = sC + row * 2176 + 1536; w = kvnw; y = kvn + row * 512; L = 512;
  }
  float ss = 0.f;
  int n4 = L >> 2;
  for (int i = threadIdx.x; i < n4; i += 256) {
    ushort4 v = ((const ushort4*)x)[i];
    float a = bf2f(v.x), bb = bf2f(v.y), c = bf2f(v.z), d = bf2f(v.w);
    ss += a * a + bb * bb + c * c + d * d;
  }
  for (int off = 32; off > 0; off >>= 1) ss += __shfl_xor(ss, off);
  __shared__ float sb[4];
  if ((threadIdx.x & 63) == 0) sb[threadIdx.x >> 6] = ss;
  __syncthreads();
  float scale = rsqrtf((sb[0] + sb[1] + sb[2] + sb[3]) / (float)L + 1e-6f);
  for (int i = threadIdx.x; i < L; i += 256)
    y[i] = f2bf(bf2f(x[i]) * scale * w[i]);
}

// ---------------- flash attention: deep split-KV, 5 blocks/CU (32KB LDS) ----------------
__global__ __launch_bounds__(256, 5) void k_attn(const unsigned short* __restrict__ qf,
                                                 const unsigned short* __restrict__ kf3,
                                                 const unsigned short* __restrict__ vt3,
                                                 unsigned short* __restrict__ o,
                                                 float* __restrict__ pO,
                                                 float* __restrict__ pml) {
  __shared__ unsigned short kbuf[64 * 192];     // 24KB, single buffer
  __shared__ unsigned short pbuf[4][16 * 64];   // 8KB: stride 64 + XOR swizzle
  int tid = threadIdx.x;
  int wave = tid >> 6, lane = tid & 63;
  int l15 = lane & 15, lhi = lane >> 4;
  int idx = blockIdx.x;
  int rp = idx >> 5, bh = idx & 31;
  int qt, part, np;
  if (rp < 32)      { qt = 24 + (rp >> 2); part = rp & 3; np = 4; }
  else if (rp < 56) { int r = rp - 32; qt = 16 + r / 3; part = r % 3; np = 3; }
  else if (rp < 72) { int r = rp - 56; qt = 8 + (r >> 1); part = r & 1; np = 2; }
  else              { qt = 79 - rp; part = 0; np = 1; }
  int nt = qt + 1;
  int t0 = nt * part / np, t1 = nt * (part + 1) / np;
  bool dodiag = (part == np - 1);
  int item;
  if (np == 1) item = -1;
  else {
    int base = (qt < 16) ? (qt - 8) * 2 : (qt < 24) ? 16 + (qt - 16) * 3 : 40 + (qt - 24) * 4;
    item = bh * 72 + base + part;
  }
  int b = bh >> 4, h = bh & 15;
  int q0 = qt * 64;
  const char* kbase = (const char*)(kf3 + (long)bh * 128 * 3072);
  const unsigned short* vfrag0 = vt3 + (long)bh * 64 * 4096 + l15 * 32 + lhi * 8;
  const unsigned short* kread = kbuf + lane * 8;
  unsigned psel = 0x07060302u;   // v_perm selector: {s0.hi16, s1.hi16}
  int pswz = (l15 & 7) << 3;     // pbuf XOR swizzle (shorts)

  // prologue: stage K tile t0
  {
    const char* src = kbase + (long)t0 * 24576 + tid * 16;
    char* dst = (char*)kbuf + tid * 16;
#pragma unroll
    for (int p = 0; p < 6; ++p) gload16(src + p * 4096, dst + p * 4096);
  }

  // Q fragments (B-operand) — loads overlap stage latency
  const unsigned short* Qb = qf + ((long)bh * SS + q0 + wave * 16 + l15) * 192 + lhi * 8;
  bf16x8 qfr[6];
#pragma unroll
  for (int ks = 0; ks < 6; ++ks) qfr[ks] = *(const bf16x8*)(Qb + ks * 32);

  float m = -3e38f, ls = 0.f;
  f32x4 acc[8] = {};
  int qin = wave * 16 + l15;

  for (int t = t0; t < t1; ++t) {
    asm volatile("s_waitcnt vmcnt(0)" ::: "memory");
    __builtin_amdgcn_s_barrier();
    __builtin_amdgcn_sched_barrier(0);

    // QK^T (swapped): sc[nf] rows k=nf*16+lhi*4+j, col q=l15; conflict-free LDS reads
    f32x4 sc[4] = {};
    __builtin_amdgcn_s_setprio(1);
#pragma unroll
    for (int ks = 0; ks < 6; ++ks) {
      bf16x8 kfr[4];
#pragma unroll
      for (int nf = 0; nf < 4; ++nf)
        kfr[nf] = *(const bf16x8*)&kread[(nf * 6 + ks) * 512];
#pragma unroll
      for (int nf = 0; nf < 4; ++nf)
        sc[nf] = mfma16(kfr[nf], qfr[ks], sc[nf]);
    }
    __builtin_amdgcn_s_setprio(0);
    __builtin_amdgcn_sched_barrier(0);
    __builtin_amdgcn_s_barrier();          // all waves done reading kbuf
    __builtin_amdgcn_sched_barrier(0);

    // V batch 0 issue (softmax covers latency)
    const unsigned short* vtb = vfrag0 + (long)t * 8192;
    bf16x8 v0[8];
#pragma unroll
    for (int nf = 0; nf < 8; ++nf) v0[nf] = *(const bf16x8*)(vtb + nf * 512);
    __builtin_amdgcn_sched_barrier(0);

    // stage K tile t+1 (WAR barrier above; hides under softmax+PV)
    if (t + 1 < t1) {
      const char* src = kbase + (long)(t + 1) * 24576 + tid * 16;
      char* dst = (char*)kbuf + tid * 16;
#pragma unroll
      for (int p = 0; p < 6; ++p) gload16(src + p * 4096, dst + p * 4096);
    }

    // online softmax, lane-local over k
    bool diag = dodiag && (t == t1 - 1);
    float mnf[4];
#pragma unroll
    for (int nf = 0; nf < 4; ++nf) {
      if (diag) {
#pragma unroll
        for (int jj = 0; jj < 4; ++jj) {
          int kin = nf * 16 + lhi * 4 + jj;
          if (kin > qin) sc[nf][jj] = -3e38f;
        }
      }
      mnf[nf] = fmaxf(fmaxf(sc[nf][0], sc[nf][1]), fmaxf(sc[nf][2], sc[nf][3]));
    }
    float mx = fmaxf(fmaxf(mnf[0], mnf[1]), fmaxf(mnf[2], mnf[3]));
    mx = fmaxf(mx, __shfl_xor(mx, 16));
    mx = fmaxf(mx, __shfl_xor(mx, 32));
    if (!__all(mx <= m + 8.f)) {      // defer-rescale (exp2 domain, THR=8)
      float mn = fmaxf(m, mx);
      float alpha = exp2f(m - mn);
      m = mn;
      ls *= alpha;
#pragma unroll
      for (int nf = 0; nf < 8; ++nf)
#pragma unroll
        for (int jj = 0; jj < 4; ++jj) acc[nf][jj] *= alpha;
    }
    float pnf[4];
#pragma unroll
    for (int nf = 0; nf < 4; ++nf) {
      float e0 = exp2f(sc[nf][0] - m), e1 = exp2f(sc[nf][1] - m);
      float e2 = exp2f(sc[nf][2] - m), e3 = exp2f(sc[nf][3] - m);
      pnf[nf] = (e0 + e1) + (e2 + e3);
      unsigned lo, hi;   // pack 2 truncated bf16 per v_perm
      asm("v_perm_b32 %0, %1, %2, %3" : "=v"(lo) : "v"(e1), "v"(e0), "s"(psel));
      asm("v_perm_b32 %0, %1, %2, %3" : "=v"(hi) : "v"(e3), "v"(e2), "s"(psel));
      uint2 pk = { lo, hi };
      *(uint2*)&pbuf[wave][l15 * 64 + ((nf * 16 + lhi * 4) ^ pswz)] = pk;
    }
    float ps = (pnf[0] + pnf[1]) + (pnf[2] + pnf[3]);
    ps += __shfl_xor(ps, 16);
    ps += __shfl_xor(ps, 32);
    ls += ps;

    // PV kk=0 with v0
    {
      bf16x8 pf = *(const bf16x8*)&pbuf[wave][l15 * 64 + ((lhi * 8) ^ pswz)];
      __builtin_amdgcn_s_setprio(1);
#pragma unroll
      for (int nf = 0; nf < 8; ++nf) acc[nf] = mfma16(v0[nf], pf, acc[nf]);
      __builtin_amdgcn_s_setprio(0);
    }
    // V batch 1 (reuses v0's registers), then PV kk=1
    bf16x8 v1[8];
#pragma unroll
    for (int nf = 0; nf < 8; ++nf) v1[nf] = *(const bf16x8*)(vtb + 4096 + nf * 512);
    {
      bf16x8 pf = *(const bf16x8*)&pbuf[wave][l15 * 64 + ((32 + lhi * 8) ^ pswz)];
      __builtin_amdgcn_s_setprio(1);
#pragma unroll
      for (int nf = 0; nf < 8; ++nf) acc[nf] = mfma16(v1[nf], pf, acc[nf]);
      __builtin_amdgcn_s_setprio(0);
    }
  }

  int qloc = wave * 16 + l15;
  if (item < 0) {
    // single: normalize + write o (row q=l15, d = nf*16+lhi*4+j)
    float invl = 1.f / ls;
    long orow = (long)b * SS + q0 + qloc;
#pragma unroll
    for (int nf = 0; nf < 8; ++nf) {
      ushort4 ov = { f2bf(acc[nf][0] * invl), f2bf(acc[nf][1] * invl),
                     f2bf(acc[nf][2] * invl), f2bf(acc[nf][3] * invl) };
      *(ushort4*)&o[orow * 2048 + h * 128 + nf * 16 + lhi * 4] = ov;
    }
  } else {
    // split: write unnormalized partials
    float* po = pO + (long)item * 8192 + qloc * 128;
#pragma unroll
    for (int nf = 0; nf < 8; ++nf)
      *(float4*)&po[nf * 16 + lhi * 4] = __builtin_bit_cast(float4, acc[nf]);
    if (lhi == 0) {
      pml[(long)item * 128 + qloc * 2] = m;
      pml[(long)item * 128 + qloc * 2 + 1] = ls;
    }
  }
}

// ---------------- merge split-KV partials (2-4 parts) -> o ----------------
__global__ __launch_bounds__(256) void k_merge(const float* __restrict__ pO,
                                               const float* __restrict__ pml,
                                               unsigned short* __restrict__ o) {
  int g = blockIdx.x;              // bh*24 + (qt-8)
  int bh = g / 24, qt = (g % 24) + 8;
  int b = bh >> 4, h = bh & 15;
  int q0 = qt * 64;
  int np = qt < 16 ? 2 : (qt < 24 ? 3 : 4);
  int base = (qt < 16) ? (qt - 8) * 2 : (qt < 24) ? 16 + (qt - 16) * 3 : 40 + (qt - 24) * 4;
  long i0 = (long)bh * 72 + base;
  __shared__ float wts[4][64];
  int tid = threadIdx.x;
  if (tid < 64) {
    float mp0 = -3e38f, mp1 = -3e38f, mp2 = -3e38f, mp3 = -3e38f;
    float lp0 = 0.f, lp1 = 0.f, lp2 = 0.f, lp3 = 0.f;
    mp0 = pml[(i0 + 0) * 128 + tid * 2]; lp0 = pml[(i0 + 0) * 128 + tid * 2 + 1];
    mp1 = pml[(i0 + 1) * 128 + tid * 2]; lp1 = pml[(i0 + 1) * 128 + tid * 2 + 1];
    if (np > 2) { mp2 = pml[(i0 + 2) * 128 + tid * 2]; lp2 = pml[(i0 + 2) * 128 + tid * 2 + 1]; }
    if (np > 3) { mp3 = pml[(i0 + 3) * 128 + tid * 2]; lp3 = pml[(i0 + 3) * 128 + tid * 2 + 1]; }
    float mm = fmaxf(fmaxf(mp0, mp1), fmaxf(mp2, mp3));
    float w0 = exp2f(mp0 - mm), w1 = exp2f(mp1 - mm);
    float w2 = (np > 2) ? exp2f(mp2 - mm) : 0.f;
    float w3 = (np > 3) ? exp2f(mp3 - mm) : 0.f;
    float inv = 1.f / (lp0 * w0 + lp1 * w1 + lp2 * w2 + lp3 * w3);
    wts[0][tid] = w0 * inv; wts[1][tid] = w1 * inv;
    wts[2][tid] = w2 * inv; wts[3][tid] = w3 * inv;
  }
  __syncthreads();
#pragma unroll
  for (int pp = 0; pp < 8; ++pp) {
    int e = pp * 256 + tid;          // float4 units: 2048 total
    int q = e >> 5, d4 = (e & 31) * 4;
    float4 s = { 0.f, 0.f, 0.f, 0.f };
#pragma unroll
    for (int p = 0; p < 4; ++p) {
      if (p < np) {
        float4 a = *(const float4*)&pO[(i0 + p) * 8192 + q * 128 + d4];
        float w = wts[p][q];
        s.x += a.x * w; s.y += a.y * w; s.z += a.z * w; s.w += a.w * w;
      }
    }
    ushort4 ov = { f2bf(s.x), f2bf(s.y), f2bf(s.z), f2bf(s.w) };
    *(ushort4*)&o[((long)b * SS + q0 + q) * 2048 + h * 128 + d4] = ov;
  }
}

extern "C" void kernel_launch(void* const* d_in, const int* in_sizes, int n_in,
                              void* d_out, int out_size, void* d_ws, size_t ws_size,
                              hipStream_t stream) {
  const float* x    = (const float*)d_in[0];
  const float* wqd  = (const float*)d_in[1];
  const float* bqd  = (const float*)d_in[2];
  const float* qnw  = (const float*)d_in[3];
  const float* wqu  = (const float*)d_in[4];
  const float* bqu  = (const float*)d_in[5];
  const float* wkvd = (const float*)d_in[6];
  const float* bkvd = (const float*)d_in[7];
  const float* kvnw = (const float*)d_in[8];
  const float* wkvu = (const float*)d_in[9];
  const float* bkvu = (const float*)d_in[10];
  const float* wout = (const float*)d_in[11];
  const float* bout = (const float*)d_in[12];
  float* out = (float*)d_out;

  char* ws = (char*)d_ws;
  size_t off = 0;
  auto alloc = [&](size_t sz) {
    char* p = ws + off;
    off += (sz + 255) & ~(size_t)255;
    return p;
  };
  unsigned short* xb    = (unsigned short*)alloc((size_t)NROWS * 2048 * 2);
  unsigned short* wqkt  = (unsigned short*)alloc((size_t)2176 * 2048 * 2);  // [wqd;wkvd]^T
  unsigned short* wqut  = (unsigned short*)alloc((size_t)3072 * 1536 * 2);
  unsigned short* wkvut = (unsigned short*)alloc((size_t)4096 * 512 * 2);
  unsigned short* woutt = (unsigned short*)alloc((size_t)2048 * 2048 * 2);
  unsigned short* qn    = (unsigned short*)alloc((size_t)NROWS * 1536 * 2);
  unsigned short* kvn   = (unsigned short*)alloc((size_t)NROWS * 512 * 2);
  unsigned short* qfb   = (unsigned short*)alloc((size_t)32 * SS * 192 * 2);
  unsigned short* kfb   = (unsigned short*)alloc((size_t)32 * SS * 192 * 2);   // kf3 tiled
  unsigned short* vtb   = (unsigned short*)alloc((size_t)32 * 128 * SS * 2);   // vt3 tiled
  unsigned short* ob    = (unsigned short*)alloc((size_t)NROWS * 2048 * 2);
  float*  mbias = (float*)alloc((size_t)2176 * 4);
  float2* rtab  = (float2*)alloc((size_t)SS * 32 * 8);
  float*  pO    = (float*)alloc((size_t)2304 * 8192 * 4);   // 75.5 MB partial O
  float*  pml   = (float*)alloc((size_t)2304 * 128 * 4);    // partial m/ls
  unsigned short* sCb = (unsigned short*)alloc((size_t)NROWS * 2176 * 2);  // merged qd|kvd (bf16)

  // fused preprocessing: convert + 5 transposes + bias merge + rope table
  k_prep<<<17417, 256, 0, stream>>>(x, xb, wqd, wqu, wkvd, wkvu, wout,
                                    wqkt, wqut, wkvut, woutt, bqd, bkvd, mbias, rtab);

  // down-projections (merged, bf16 out): sCb = x @ [wqd|wkvd] + bias
  k_gemm_c16<<<32 * 17, 256, 0, stream>>>(xb, wqkt, mbias, sCb, NROWS, 2176, 2048);

  // both rmsnorms in one launch
  k_rmsnorm2<<<2 * NROWS, 256, 0, stream>>>(sCb, qnw, kvnw, qn, kvn);

  // up-projections + krope in one launch
  k_up<<<2816, 256, 0, stream>>>(qn, wqut, bqu, kvn, wkvut, bkvu, sCb, rtab,
                                 qfb, kfb, vtb);

  // attention: deep split-KV (2560 blocks, max 9 iters, 5 blocks/CU) + merge
  k_attn<<<2560, 256, 0, stream>>>(qfb, kfb, vtb, ob, pO, pml);
  k_merge<<<768, 256, 0, stream>>>(pO, pml, ob);

  // output projection
  k_gemm<<<32 * 16, 256, 0, stream>>>(ob, woutt, bout, out, NROWS, 2048, 2048);
}

// Round 17
// 405.325 us; speedup vs baseline: 1.5031x; 1.5031x over previous
//
#include <hip/hip_runtime.h>
#include <hip/hip_bf16.h>
#include <math.h>

#define HH 16
#define SS 2048
#define BBATCH 2
#define NROWS 4096   // B*S

typedef __attribute__((ext_vector_type(8))) __bf16 bf16x8;
typedef __attribute__((ext_vector_type(4))) float f32x4;
typedef const __attribute__((address_space(1))) unsigned int* gas1_t;
typedef __attribute__((address_space(3))) unsigned int* las3_t;

__device__ __forceinline__ unsigned short f2bf(float f) {
  unsigned u = __builtin_bit_cast(unsigned, f);
  u += 0x7fffu + ((u >> 16) & 1u);
  return (unsigned short)(u >> 16);
}
__device__ __forceinline__ float bf2f(unsigned short u) {
  return __builtin_bit_cast(float, (unsigned)u << 16);
}

__device__ __forceinline__ void gload16(const void* g, void* l) {
  __builtin_amdgcn_global_load_lds((gas1_t)g, (las3_t)l, 16, 0, 0);
}
__device__ __forceinline__ f32x4 mfma16(bf16x8 a, bf16x8 b, f32x4 c) {
  return __builtin_amdgcn_mfma_f32_16x16x32_bf16(a, b, c, 0, 0, 0);
}

// ---------------- transpose body: W (K,N) f32 -> Wt (Npad,K) bf16 ----------------
__device__ __forceinline__ void transpose_body(const float* __restrict__ W,
                                               unsigned short* __restrict__ Wt,
                                               int K, int N, int Npad,
                                               int bx, int by, float (*tile)[33], int tid) {
  int n0 = bx * 32, k0 = by * 32;
  int tx = tid & 31, ty = tid >> 5;
  for (int i = ty; i < 32; i += 8) {
    int k = k0 + i, n = n0 + tx;
    tile[i][tx] = (k < K && n < N) ? W[(long)k * N + n] : 0.f;
  }
  __syncthreads();
  for (int i = ty; i < 32; i += 8) {
    int n = n0 + i, k = k0 + tx;
    if (n < Npad && k < K) Wt[(long)n * K + k] = f2bf(tile[tx][i]);
  }
}

// ---------------- fused preprocessing: convert + 5 transposes + bias + rope table ----------------
__global__ __launch_bounds__(256) void k_prep(const float* __restrict__ x,
                                              unsigned short* __restrict__ xb,
                                              const float* __restrict__ wqd,
                                              const float* __restrict__ wqu,
                                              const float* __restrict__ wkvd,
                                              const float* __restrict__ wkvu,
                                              const float* __restrict__ wout,
                                              unsigned short* __restrict__ wqkt,
                                              unsigned short* __restrict__ wqut,
                                              unsigned short* __restrict__ wkvut,
                                              unsigned short* __restrict__ woutt,
                                              const float* __restrict__ bqd,
                                              const float* __restrict__ bkvd,
                                              float* __restrict__ mbias,
                                              float2* __restrict__ rtab) {
  __shared__ float tile[32][33];
  int blk = blockIdx.x;
  int tid = threadIdx.x;
  if (blk < 2048) {
    long n4 = (long)NROWS * 2048 / 4;
    for (long i = (long)blk * 256 + tid; i < n4; i += 2048 * 256) {
      float4 v = ((const float4*)x)[i];
      ushort4 o = { f2bf(v.x), f2bf(v.y), f2bf(v.z), f2bf(v.w) };
      ((ushort4*)xb)[i] = o;
    }
  } else if (blk < 5120) {
    int t = blk - 2048;
    transpose_body(wqd, wqkt, 2048, 1536, 1536, t % 48, t / 48, tile, tid);
  } else if (blk < 9728) {
    int t = blk - 5120;
    transpose_body(wqu, wqut, 1536, 3072, 3072, t % 96, t / 96, tile, tid);
  } else if (blk < 11008) {
    int t = blk - 9728;
    transpose_body(wkvd, wqkt + (size_t)1536 * 2048, 2048, 576, 640, t % 20, t / 20, tile, tid);
  } else if (blk < 13056) {
    int t = blk - 11008;
    transpose_body(wkvu, wkvut, 512, 4096, 4096, t % 128, t / 128, tile, tid);
  } else if (blk < 17152) {
    int t = blk - 13056;
    transpose_body(wout, woutt, 2048, 2048, 2048, t % 64, t / 64, tile, tid);
  } else if (blk < 17161) {
    int i = (blk - 17152) * 256 + tid;
    if (i < 2176) mbias[i] = i < 1536 ? bqd[i] : (i < 2112 ? bkvd[i - 1536] : 0.f);
  } else {
    int t = blk - 17161;                    // 256 blocks, 8 s each
    int s = t * 8 + (tid >> 5);
    int i = tid & 31;
    float inv = powf(10000.f, -(float)i / 32.f);
    float ang = (float)s * inv;
    float sn, cs;
    sincosf(ang, &sn, &cs);
    rtab[s * 32 + i] = make_float2(cs, sn);
  }
}

// ---------------- GEMM: C(M,N) f32 = A(M,K)bf16 * Bt(Npad,K)bf16 + bias ----------------
__global__ __launch_bounds__(256) void k_gemm(const unsigned short* __restrict__ A,
                                              const unsigned short* __restrict__ Bt,
                                              const float* __restrict__ bias,
                                              float* __restrict__ C,
                                              int M, int N, int K) {
  __shared__ unsigned short lA[128 * 32];
  __shared__ unsigned short lB[128 * 32];
  int tid = threadIdx.x;
  int wave = tid >> 6, lane = tid & 63;
  int l15 = lane & 15, lhi = lane >> 4;
  int ntn = (N + 127) >> 7;
  int tm = blockIdx.x / ntn, tn = blockIdx.x % ntn;
  long row0 = (long)tm * 128, col0 = (long)tn * 128;
  int wr = wave >> 1, wc = wave & 1;

  const unsigned short* gA = A + (row0 + (tid >> 2)) * K + (tid & 3) * 8;
  const unsigned short* gB = Bt + (col0 + (tid >> 2)) * K + (tid & 3) * 8;
  unsigned short* lA0 = &lA[tid * 8];
  unsigned short* lB0 = &lB[tid * 8];

  f32x4 acc[4][4] = {};
  for (int k0 = 0; k0 < K; k0 += 32) {
    __syncthreads();
    gload16(gA + k0, lA0);
    gload16(gA + (long)64 * K + k0, lA0 + 2048);
    gload16(gB + k0, lB0);
    gload16(gB + (long)64 * K + k0, lB0 + 2048);
    asm volatile("s_waitcnt vmcnt(0)" ::: "memory");
    __syncthreads();
    bf16x8 af[4], bfr[4];
#pragma unroll
    for (int i = 0; i < 4; ++i) {
      af[i]  = *(const bf16x8*)&lA[(wr * 64 + i * 16 + l15) * 32 + lhi * 8];
      bfr[i] = *(const bf16x8*)&lB[(wc * 64 + i * 16 + l15) * 32 + lhi * 8];
    }
#pragma unroll
    for (int i = 0; i < 4; ++i)
#pragma unroll
      for (int j = 0; j < 4; ++j)
        acc[i][j] = mfma16(af[i], bfr[j], acc[i][j]);
  }
#pragma unroll
  for (int i = 0; i < 4; ++i)
#pragma unroll
    for (int j = 0; j < 4; ++j) {
      long r = row0 + wr * 64 + i * 16 + lhi * 4;
      long c = col0 + wc * 64 + j * 16 + l15;
      if (c < N) {
        float bv = bias[c];
#pragma unroll
        for (int rr = 0; rr < 4; ++rr)
          C[(r + rr) * N + c] = acc[i][j][rr] + bv;
      }
    }
}

// ---------------- GEMM with bf16 output (down-proj -> sC bf16) ----------------
__global__ __launch_bounds__(256) void k_gemm_c16(const unsigned short* __restrict__ A,
                                                  const unsigned short* __restrict__ Bt,
                                                  const float* __restrict__ bias,
                                                  unsigned short* __restrict__ C,
                                                  int M, int N, int K) {
  __shared__ unsigned short lA[128 * 32];
  __shared__ unsigned short lB[128 * 32];
  int tid = threadIdx.x;
  int wave = tid >> 6, lane = tid & 63;
  int l15 = lane & 15, lhi = lane >> 4;
  int ntn = (N + 127) >> 7;
  int tm = blockIdx.x / ntn, tn = blockIdx.x % ntn;
  long row0 = (long)tm * 128, col0 = (long)tn * 128;
  int wr = wave >> 1, wc = wave & 1;

  const unsigned short* gA = A + (row0 + (tid >> 2)) * K + (tid & 3) * 8;
  const unsigned short* gB = Bt + (col0 + (tid >> 2)) * K + (tid & 3) * 8;
  unsigned short* lA0 = &lA[tid * 8];
  unsigned short* lB0 = &lB[tid * 8];

  f32x4 acc[4][4] = {};
  for (int k0 = 0; k0 < K; k0 += 32) {
    __syncthreads();
    gload16(gA + k0, lA0);
    gload16(gA + (long)64 * K + k0, lA0 + 2048);
    gload16(gB + k0, lB0);
    gload16(gB + (long)64 * K + k0, lB0 + 2048);
    asm volatile("s_waitcnt vmcnt(0)" ::: "memory");
    __syncthreads();
    bf16x8 af[4], bfr[4];
#pragma unroll
    for (int i = 0; i < 4; ++i) {
      af[i]  = *(const bf16x8*)&lA[(wr * 64 + i * 16 + l15) * 32 + lhi * 8];
      bfr[i] = *(const bf16x8*)&lB[(wc * 64 + i * 16 + l15) * 32 + lhi * 8];
    }
#pragma unroll
    for (int i = 0; i < 4; ++i)
#pragma unroll
      for (int j = 0; j < 4; ++j)
        acc[i][j] = mfma16(af[i], bfr[j], acc[i][j]);
  }
#pragma unroll
  for (int i = 0; i < 4; ++i)
#pragma unroll
    for (int j = 0; j < 4; ++j) {
      long r = row0 + wr * 64 + i * 16 + lhi * 4;
      long c = col0 + wc * 64 + j * 16 + l15;
      if (c < N) {
        float bv = bias[c];
#pragma unroll
        for (int rr = 0; rr < 4; ++rr)
          C[(r + rr) * N + c] = f2bf(acc[i][j][rr] + bv);
      }
    }
}

// ---------------- merged up-projections + krope in ONE launch ----------------
// blocks [0,768): qf GEMM (N=3072, K=1536, fused rope/scale epilogue)
// blocks [768,1792): kv GEMM (N=4096, K=512, fused kf3/vt3 tiled epilogue)
// blocks [1792,2816): krope (4 rows/block, table-based)
__global__ __launch_bounds__(256) void k_up(const unsigned short* __restrict__ qn,
                                            const unsigned short* __restrict__ wqut,
                                            const float* __restrict__ bqu,
                                            const unsigned short* __restrict__ kvn,
                                            const unsigned short* __restrict__ wkvut,
                                            const float* __restrict__ bkvu,
                                            const unsigned short* __restrict__ sCb,
                                            const float2* __restrict__ rtab,
                                            unsigned short* __restrict__ qf,
                                            unsigned short* __restrict__ kf3,
                                            unsigned short* __restrict__ vt3) {
  __shared__ unsigned short smem[16384];   // 32KB
  unsigned short* lA = smem;
  unsigned short* lB = smem + 4096;
  int blk = blockIdx.x;
  int tid = threadIdx.x;
  int wave = tid >> 6, lane = tid & 63;
  int l15 = lane & 15, lhi = lane >> 4;
  int wr = wave >> 1, wc = wave & 1;

  if (blk < 768) {
    // ---- qf GEMM ----
    const int N = 3072, K = 1536;
    int tm = blk / 24, tn = blk % 24;
    long row0 = (long)tm * 128, col0 = (long)tn * 128;
    const unsigned short* gA = qn + (row0 + (tid >> 2)) * K + (tid & 3) * 8;
    const unsigned short* gB = wqut + (col0 + (tid >> 2)) * K + (tid & 3) * 8;
    unsigned short* lA0 = &lA[tid * 8];
    unsigned short* lB0 = &lB[tid * 8];
    f32x4 acc[4][4] = {};
    for (int k0 = 0; k0 < K; k0 += 32) {
      __syncthreads();
      gload16(gA + k0, lA0);
      gload16(gA + (long)64 * K + k0, lA0 + 2048);
      gload16(gB + k0, lB0);
      gload16(gB + (long)64 * K + k0, lB0 + 2048);
      asm volatile("s_waitcnt vmcnt(0)" ::: "memory");
      __syncthreads();
      bf16x8 af[4], bfr[4];
#pragma unroll
      for (int i = 0; i < 4; ++i) {
        af[i]  = *(const bf16x8*)&lA[(wr * 64 + i * 16 + l15) * 32 + lhi * 8];
        bfr[i] = *(const bf16x8*)&lB[(wc * 64 + i * 16 + l15) * 32 + lhi * 8];
      }
#pragma unroll
      for (int i = 0; i < 4; ++i)
#pragma unroll
        for (int j = 0; j < 4; ++j)
          acc[i][j] = mfma16(af[i], bfr[j], acc[i][j]);
    }
    const float scq = 0.07216878364870322f * 1.4426950408889634f;  // 192^-0.5 * log2(e)
    int base = (int)col0 + wc * 64;
    int h = base / 192;
    int m192 = base - h * 192;   // 0, 64, or 128 (wave-uniform)
    float bv[4];
#pragma unroll
    for (int j = 0; j < 4; ++j) bv[j] = bqu[base + j * 16 + l15];
#pragma unroll
    for (int i = 0; i < 4; ++i) {
#pragma unroll
      for (int rr = 0; rr < 4; ++rr) {
        long r = row0 + wr * 64 + i * 16 + lhi * 4 + rr;
        int s = (int)(r & 2047), b = (int)(r >> 11);
        unsigned short* dst = qf + (((long)(b * HH + h)) * SS + s) * 192;
        if (m192 < 128) {
#pragma unroll
          for (int j = 0; j < 4; ++j)
            dst[m192 + j * 16 + l15] = f2bf((acc[i][j][rr] + bv[j]) * scq);
        } else {
#pragma unroll
          for (int j = 0; j < 2; ++j) {
            int ifq = j * 16 + l15;
            float2 cs = rtab[s * 32 + ifq];
            float v1 = acc[i][j][rr] + bv[j];
            float v2 = acc[i][j + 2][rr] + bv[j + 2];
            dst[128 + ifq] = f2bf((v1 * cs.x - v2 * cs.y) * scq);
            dst[160 + ifq] = f2bf((v2 * cs.x + v1 * cs.y) * scq);
          }
        }
      }
    }
  } else if (blk < 1792) {
    // ---- kv GEMM with tiled epilogue ----
    const int N = 4096, K = 512;
    int b2 = blk - 768;
    int tm = b2 / 32, tn = b2 % 32;
    long row0 = (long)tm * 128, col0 = (long)tn * 128;
    const unsigned short* gA = kvn + (row0 + (tid >> 2)) * K + (tid & 3) * 8;
    const unsigned short* gB = wkvut + (col0 + (tid >> 2)) * K + (tid & 3) * 8;
    unsigned short* lA0 = &lA[tid * 8];
    unsigned short* lB0 = &lB[tid * 8];
    f32x4 acc[4][4] = {};
    for (int k0 = 0; k0 < K; k0 += 32) {
      __syncthreads();
      gload16(gA + k0, lA0);
      gload16(gA + (long)64 * K + k0, lA0 + 2048);
      gload16(gB + k0, lB0);
      gload16(gB + (long)64 * K + k0, lB0 + 2048);
      asm volatile("s_waitcnt vmcnt(0)" ::: "memory");
      __syncthreads();
      bf16x8 af[4], bfr[4];
#pragma unroll
      for (int i = 0; i < 4; ++i) {
        af[i]  = *(const bf16x8*)&lA[(wr * 64 + i * 16 + l15) * 32 + lhi * 8];
        bfr[i] = *(const bf16x8*)&lB[(wc * 64 + i * 16 + l15) * 32 + lhi * 8];
      }
#pragma unroll
      for (int i = 0; i < 4; ++i)
#pragma unroll
        for (int j = 0; j < 4; ++j)
          acc[i][j] = mfma16(af[i], bfr[j], acc[i][j]);
    }
    int base = (int)col0 + wc * 64;
    int h = base >> 8;
    bool isv = (base & 255) >= 128;   // block-uniform (tn parity)
    float bv[4];
#pragma unroll
    for (int j = 0; j < 4; ++j) bv[j] = bkvu[base + j * 16 + l15];
    int b = (int)(row0 >> 11);
    long bh = (long)b * HH + h;
    int lrb = wr * 64;
    __syncthreads();
    if (isv) {
#pragma unroll
      for (int i = 0; i < 4; ++i) {
        int lr = lrb + i * 16 + lhi * 4;
#pragma unroll
        for (int j = 0; j < 4; ++j) {
          int lc = wc * 64 + j * 16 + l15;
          ushort4 pk = { f2bf(acc[i][j][0] + bv[j]), f2bf(acc[i][j][1] + bv[j]),
                         f2bf(acc[i][j][2] + bv[j]), f2bf(acc[i][j][3] + bv[j]) };
          *(ushort4*)&smem[((lr >> 5) << 12) + lc * 32 + (lr & 31)] = pk;
        }
      }
      __syncthreads();
      long dst0 = (bh * 64 + ((row0 & 2047) >> 5)) * 4096;
#pragma unroll
      for (int p = 0; p < 8; ++p) {
        int e = p * 256 + tid;
        *(uint4*)&vt3[dst0 + e * 8] = *(uint4*)&smem[e * 8];
      }
    } else {
#pragma unroll
      for (int i = 0; i < 4; ++i) {
        int lr0 = lrb + i * 16 + lhi * 4;
#pragma unroll
        for (int j = 0; j < 4; ++j) {
          int c = (base & 255) + j * 16 + l15;   // 0..127
          int tbase = ((lr0 >> 4) << 11) + ((c >> 5) << 9) + (((c >> 3) & 3) << 7) + (c & 7);
#pragma unroll
          for (int rr = 0; rr < 4; ++rr)
            smem[tbase + ((lr0 + rr) & 15) * 8] = f2bf(acc[i][j][rr] + bv[j]);
        }
      }
      __syncthreads();
      long kb3 = (bh * 128 + ((row0 & 2047) >> 4)) * 3072;
#pragma unroll
      for (int p = 0; p < 8; ++p) {
        int e = p * 256 + tid;
        int tile = e >> 6;
        int off = (e & 63) * 8;
        long dst = kb3 + ((long)(tile >> 2) * 6 + (tile & 3)) * 512 + off;
        *(uint4*)&kf3[dst] = *(uint4*)&smem[tile * 512 + off];
      }
    }
  } else {
    // ---- krope: 4 rows per block ----
    int t = blk - 1792;
    int bs = t * 4 + (tid >> 6);
    int s = bs & (SS - 1), b = bs >> 11;
    const unsigned short* src = sCb + (long)bs * 2176 + 2048;
    int i = lane & 31;
    float2 cs = rtab[s * 32 + i];
    float t1 = bf2f(src[i]), t2 = bf2f(src[32 + i]);
    float v = (lane < 32) ? (t1 * cs.x - t2 * cs.y) : (t2 * cs.x + t1 * cs.y);
    unsigned short bv = f2bf(v);
    int d = 128 + lane;
    long inner = (long)(d >> 5) * 512 + ((d >> 3) & 3) * 128 + (s & 15) * 8 + (d & 7);
#pragma unroll
    for (int h = 0; h < HH; ++h) {
      long kblk = ((long)(b * HH + h) * 128 + (s >> 4)) * 6;
      kf3[kblk * 512 + inner] = bv;
    }
  }
}

// ---------------- merged RMSNorm (q rows then kv rows): bf16 -> bf16 ----------------
__global__ __launch_bounds__(256) void k_rmsnorm2(const unsigned short* __restrict__ sC,
                                                  const float* __restrict__ qnw,
                                                  const float* __restrict__ kvnw,
                                                  unsigned short* __restrict__ qn,
                                                  unsigned short* __restrict__ kvn) {
  int blk = blockIdx.x;
  long row;
  const unsigned short* x;
  const float* w;
  unsigned short* y;
  int L;
  if (blk < NROWS) {
    row = blk; x = sC + row * 2176; w = qnw; y = qn + row * 1536; L = 1536;
  } else {
    row = blk - NROWS; x = sC + row * 2176 + 1536; w = kvnw; y = kvn + row * 512; L = 512;
  }
  float ss = 0.f;
  int n4 = L >> 2;
  for (int i = threadIdx.x; i < n4; i += 256) {
    ushort4 v = ((const ushort4*)x)[i];
    float a = bf2f(v.x), bb = bf2f(v.y), c = bf2f(v.z), d = bf2f(v.w);
    ss += a * a + bb * bb + c * c + d * d;
  }
  for (int off = 32; off > 0; off >>= 1) ss += __shfl_xor(ss, off);
  __shared__ float sb[4];
  if ((threadIdx.x & 63) == 0) sb[threadIdx.x >> 6] = ss;
  __syncthreads();
  float scale = rsqrtf((sb[0] + sb[1] + sb[2] + sb[3]) / (float)L + 1e-6f);
  for (int i = threadIdx.x; i < L; i += 256)
    y[i] = f2bf(bf2f(x[i]) * scale * w[i]);
}

// ---------------- flash attention: deep split-KV, 32KB LDS (5 blocks/CU natural) ----------------
// launch_bounds(256,4): allocator budget 128/wave (actual ~64, no spill);
// hardware occupancy = min(LDS 160/32=5, VGPR) = 5 blocks/CU.
__global__ __launch_bounds__(256, 4) void k_attn(const unsigned short* __restrict__ qf,
                                                 const unsigned short* __restrict__ kf3,
                                                 const unsigned short* __restrict__ vt3,
                                                 unsigned short* __restrict__ o,
                                                 float* __restrict__ pO,
                                                 float* __restrict__ pml) {
  __shared__ unsigned short kbuf[64 * 192];     // 24KB, single buffer
  __shared__ unsigned short pbuf[4][16 * 64];   // 8KB: stride 64 + XOR swizzle
  int tid = threadIdx.x;
  int wave = tid >> 6, lane = tid & 63;
  int l15 = lane & 15, lhi = lane >> 4;
  int idx = blockIdx.x;
  int rp = idx >> 5, bh = idx & 31;
  int qt, part, np;
  if (rp < 32)      { qt = 24 + (rp >> 2); part = rp & 3; np = 4; }
  else if (rp < 56) { int r = rp - 32; qt = 16 + r / 3; part = r % 3; np = 3; }
  else if (rp < 72) { int r = rp - 56; qt = 8 + (r >> 1); part = r & 1; np = 2; }
  else              { qt = 79 - rp; part = 0; np = 1; }
  int nt = qt + 1;
  int t0 = nt * part / np, t1 = nt * (part + 1) / np;
  bool dodiag = (part == np - 1);
  int item;
  if (np == 1) item = -1;
  else {
    int base = (qt < 16) ? (qt - 8) * 2 : (qt < 24) ? 16 + (qt - 16) * 3 : 40 + (qt - 24) * 4;
    item = bh * 72 + base + part;
  }
  int b = bh >> 4, h = bh & 15;
  int q0 = qt * 64;
  const char* kbase = (const char*)(kf3 + (long)bh * 128 * 3072);
  const unsigned short* vfrag0 = vt3 + (long)bh * 64 * 4096 + l15 * 32 + lhi * 8;
  const unsigned short* kread = kbuf + lane * 8;
  unsigned psel = 0x07060302u;   // v_perm selector: {s0.hi16, s1.hi16}
  int pswz = (l15 & 7) << 3;     // pbuf XOR swizzle (shorts)

  // prologue: stage K tile t0
  {
    const char* src = kbase + (long)t0 * 24576 + tid * 16;
    char* dst = (char*)kbuf + tid * 16;
#pragma unroll
    for (int p = 0; p < 6; ++p) gload16(src + p * 4096, dst + p * 4096);
  }

  // Q fragments (B-operand) — loads overlap stage latency
  const unsigned short* Qb = qf + ((long)bh * SS + q0 + wave * 16 + l15) * 192 + lhi * 8;
  bf16x8 qfr[6];
#pragma unroll
  for (int ks = 0; ks < 6; ++ks) qfr[ks] = *(const bf16x8*)(Qb + ks * 32);

  float m = -3e38f, ls = 0.f;
  f32x4 acc[8] = {};
  int qin = wave * 16 + l15;

  for (int t = t0; t < t1; ++t) {
    asm volatile("s_waitcnt vmcnt(0)" ::: "memory");
    __builtin_amdgcn_s_barrier();
    __builtin_amdgcn_sched_barrier(0);

    // QK^T (swapped): sc[nf] rows k=nf*16+lhi*4+j, col q=l15; conflict-free LDS reads
    f32x4 sc[4] = {};
    __builtin_amdgcn_s_setprio(1);
#pragma unroll
    for (int ks = 0; ks < 6; ++ks) {
      bf16x8 kfr[4];
#pragma unroll
      for (int nf = 0; nf < 4; ++nf)
        kfr[nf] = *(const bf16x8*)&kread[(nf * 6 + ks) * 512];
#pragma unroll
      for (int nf = 0; nf < 4; ++nf)
        sc[nf] = mfma16(kfr[nf], qfr[ks], sc[nf]);
    }
    __builtin_amdgcn_s_setprio(0);
    __builtin_amdgcn_sched_barrier(0);
    __builtin_amdgcn_s_barrier();          // all waves done reading kbuf
    __builtin_amdgcn_sched_barrier(0);

    // V batch 0 issue (softmax covers latency)
    const unsigned short* vtb = vfrag0 + (long)t * 8192;
    bf16x8 v0[8];
#pragma unroll
    for (int nf = 0; nf < 8; ++nf) v0[nf] = *(const bf16x8*)(vtb + nf * 512);
    __builtin_amdgcn_sched_barrier(0);

    // stage K tile t+1 (WAR barrier above; hides under softmax+PV)
    if (t + 1 < t1) {
      const char* src = kbase + (long)(t + 1) * 24576 + tid * 16;
      char* dst = (char*)kbuf + tid * 16;
#pragma unroll
      for (int p = 0; p < 6; ++p) gload16(src + p * 4096, dst + p * 4096);
    }

    // online softmax, lane-local over k
    bool diag = dodiag && (t == t1 - 1);
    float mnf[4];
#pragma unroll
    for (int nf = 0; nf < 4; ++nf) {
      if (diag) {
#pragma unroll
        for (int jj = 0; jj < 4; ++jj) {
          int kin = nf * 16 + lhi * 4 + jj;
          if (kin > qin) sc[nf][jj] = -3e38f;
        }
      }
      mnf[nf] = fmaxf(fmaxf(sc[nf][0], sc[nf][1]), fmaxf(sc[nf][2], sc[nf][3]));
    }
    float mx = fmaxf(fmaxf(mnf[0], mnf[1]), fmaxf(mnf[2], mnf[3]));
    mx = fmaxf(mx, __shfl_xor(mx, 16));
    mx = fmaxf(mx, __shfl_xor(mx, 32));
    if (!__all(mx <= m + 8.f)) {      // defer-rescale (exp2 domain, THR=8)
      float mn = fmaxf(m, mx);
      float alpha = exp2f(m - mn);
      m = mn;
      ls *= alpha;
#pragma unroll
      for (int nf = 0; nf < 8; ++nf)
#pragma unroll
        for (int jj = 0; jj < 4; ++jj) acc[nf][jj] *= alpha;
    }
    float pnf[4];
#pragma unroll
    for (int nf = 0; nf < 4; ++nf) {
      float e0 = exp2f(sc[nf][0] - m), e1 = exp2f(sc[nf][1] - m);
      float e2 = exp2f(sc[nf][2] - m), e3 = exp2f(sc[nf][3] - m);
      pnf[nf] = (e0 + e1) + (e2 + e3);
      unsigned lo, hi;   // pack 2 truncated bf16 per v_perm
      asm("v_perm_b32 %0, %1, %2, %3" : "=v"(lo) : "v"(e1), "v"(e0), "s"(psel));
      asm("v_perm_b32 %0, %1, %2, %3" : "=v"(hi) : "v"(e3), "v"(e2), "s"(psel));
      uint2 pk = { lo, hi };
      *(uint2*)&pbuf[wave][l15 * 64 + ((nf * 16 + lhi * 4) ^ pswz)] = pk;
    }
    float ps = (pnf[0] + pnf[1]) + (pnf[2] + pnf[3]);
    ps += __shfl_xor(ps, 16);
    ps += __shfl_xor(ps, 32);
    ls += ps;

    // PV kk=0 with v0
    {
      bf16x8 pf = *(const bf16x8*)&pbuf[wave][l15 * 64 + ((lhi * 8) ^ pswz)];
      __builtin_amdgcn_s_setprio(1);
#pragma unroll
      for (int nf = 0; nf < 8; ++nf) acc[nf] = mfma16(v0[nf], pf, acc[nf]);
      __builtin_amdgcn_s_setprio(0);
    }
    // V batch 1 (reuses v0's registers), then PV kk=1
    bf16x8 v1[8];
#pragma unroll
    for (int nf = 0; nf < 8; ++nf) v1[nf] = *(const bf16x8*)(vtb + 4096 + nf * 512);
    {
      bf16x8 pf = *(const bf16x8*)&pbuf[wave][l15 * 64 + ((32 + lhi * 8) ^ pswz)];
      __builtin_amdgcn_s_setprio(1);
#pragma unroll
      for (int nf = 0; nf < 8; ++nf) acc[nf] = mfma16(v1[nf], pf, acc[nf]);
      __builtin_amdgcn_s_setprio(0);
    }
  }

  int qloc = wave * 16 + l15;
  if (item < 0) {
    // single: normalize + write o (row q=l15, d = nf*16+lhi*4+j)
    float invl = 1.f / ls;
    long orow = (long)b * SS + q0 + qloc;
#pragma unroll
    for (int nf = 0; nf < 8; ++nf) {
      ushort4 ov = { f2bf(acc[nf][0] * invl), f2bf(acc[nf][1] * invl),
                     f2bf(acc[nf][2] * invl), f2bf(acc[nf][3] * invl) };
      *(ushort4*)&o[orow * 2048 + h * 128 + nf * 16 + lhi * 4] = ov;
    }
  } else {
    // split: write unnormalized partials
    float* po = pO + (long)item * 8192 + qloc * 128;
#pragma unroll
    for (int nf = 0; nf < 8; ++nf)
      *(float4*)&po[nf * 16 + lhi * 4] = __builtin_bit_cast(float4, acc[nf]);
    if (lhi == 0) {
      pml[(long)item * 128 + qloc * 2] = m;
      pml[(long)item * 128 + qloc * 2 + 1] = ls;
    }
  }
}

// ---------------- merge split-KV partials (2-4 parts) -> o ----------------
__global__ __launch_bounds__(256) void k_merge(const float* __restrict__ pO,
                                               const float* __restrict__ pml,
                                               unsigned short* __restrict__ o) {
  int g = blockIdx.x;              // bh*24 + (qt-8)
  int bh = g / 24, qt = (g % 24) + 8;
  int b = bh >> 4, h = bh & 15;
  int q0 = qt * 64;
  int np = qt < 16 ? 2 : (qt < 24 ? 3 : 4);
  int base = (qt < 16) ? (qt - 8) * 2 : (qt < 24) ? 16 + (qt - 16) * 3 : 40 + (qt - 24) * 4;
  long i0 = (long)bh * 72 + base;
  __shared__ float wts[4][64];
  int tid = threadIdx.x;
  if (tid < 64) {
    float mp0 = -3e38f, mp1 = -3e38f, mp2 = -3e38f, mp3 = -3e38f;
    float lp0 = 0.f, lp1 = 0.f, lp2 = 0.f, lp3 = 0.f;
    mp0 = pml[(i0 + 0) * 128 + tid * 2]; lp0 = pml[(i0 + 0) * 128 + tid * 2 + 1];
    mp1 = pml[(i0 + 1) * 128 + tid * 2]; lp1 = pml[(i0 + 1) * 128 + tid * 2 + 1];
    if (np > 2) { mp2 = pml[(i0 + 2) * 128 + tid * 2]; lp2 = pml[(i0 + 2) * 128 + tid * 2 + 1]; }
    if (np > 3) { mp3 = pml[(i0 + 3) * 128 + tid * 2]; lp3 = pml[(i0 + 3) * 128 + tid * 2 + 1]; }
    float mm = fmaxf(fmaxf(mp0, mp1), fmaxf(mp2, mp3));
    float w0 = exp2f(mp0 - mm), w1 = exp2f(mp1 - mm);
    float w2 = (np > 2) ? exp2f(mp2 - mm) : 0.f;
    float w3 = (np > 3) ? exp2f(mp3 - mm) : 0.f;
    float inv = 1.f / (lp0 * w0 + lp1 * w1 + lp2 * w2 + lp3 * w3);
    wts[0][tid] = w0 * inv; wts[1][tid] = w1 * inv;
    wts[2][tid] = w2 * inv; wts[3][tid] = w3 * inv;
  }
  __syncthreads();
#pragma unroll
  for (int pp = 0; pp < 8; ++pp) {
    int e = pp * 256 + tid;          // float4 units: 2048 total
    int q = e >> 5, d4 = (e & 31) * 4;
    float4 s = { 0.f, 0.f, 0.f, 0.f };
#pragma unroll
    for (int p = 0; p < 4; ++p) {
      if (p < np) {
        float4 a = *(const float4*)&pO[(i0 + p) * 8192 + q * 128 + d4];
        float w = wts[p][q];
        s.x += a.x * w; s.y += a.y * w; s.z += a.z * w; s.w += a.w * w;
      }
    }
    ushort4 ov = { f2bf(s.x), f2bf(s.y), f2bf(s.z), f2bf(s.w) };
    *(ushort4*)&o[((long)b * SS + q0 + q) * 2048 + h * 128 + d4] = ov;
  }
}

extern "C" void kernel_launch(void* const* d_in, const int* in_sizes, int n_in,
                              void* d_out, int out_size, void* d_ws, size_t ws_size,
                              hipStream_t stream) {
  const float* x    = (const float*)d_in[0];
  const float* wqd  = (const float*)d_in[1];
  const float* bqd  = (const float*)d_in[2];
  const float* qnw  = (const float*)d_in[3];
  const float* wqu  = (const float*)d_in[4];
  const float* bqu  = (const float*)d_in[5];
  const float* wkvd = (const float*)d_in[6];
  const float* bkvd = (const float*)d_in[7];
  const float* kvnw = (const float*)d_in[8];
  const float* wkvu = (const float*)d_in[9];
  const float* bkvu = (const float*)d_in[10];
  const float* wout = (const float*)d_in[11];
  const float* bout = (const float*)d_in[12];
  float* out = (float*)d_out;

  char* ws = (char*)d_ws;
  size_t off = 0;
  auto alloc = [&](size_t sz) {
    char* p = ws + off;
    off += (sz + 255) & ~(size_t)255;
    return p;
  };
  unsigned short* xb    = (unsigned short*)alloc((size_t)NROWS * 2048 * 2);
  unsigned short* wqkt  = (unsigned short*)alloc((size_t)2176 * 2048 * 2);  // [wqd;wkvd]^T
  unsigned short* wqut  = (unsigned short*)alloc((size_t)3072 * 1536 * 2);
  unsigned short* wkvut = (unsigned short*)alloc((size_t)4096 * 512 * 2);
  unsigned short* woutt = (unsigned short*)alloc((size_t)2048 * 2048 * 2);
  unsigned short* qn    = (unsigned short*)alloc((size_t)NROWS * 1536 * 2);
  unsigned short* kvn   = (unsigned short*)alloc((size_t)NROWS * 512 * 2);
  unsigned short* qfb   = (unsigned short*)alloc((size_t)32 * SS * 192 * 2);
  unsigned short* kfb   = (unsigned short*)alloc((size_t)32 * SS * 192 * 2);   // kf3 tiled
  unsigned short* vtb   = (unsigned short*)alloc((size_t)32 * 128 * SS * 2);   // vt3 tiled
  unsigned short* ob    = (unsigned short*)alloc((size_t)NROWS * 2048 * 2);
  float*  mbias = (float*)alloc((size_t)2176 * 4);
  float2* rtab  = (float2*)alloc((size_t)SS * 32 * 8);
  float*  pO    = (float*)alloc((size_t)2304 * 8192 * 4);   // 75.5 MB partial O
  float*  pml   = (float*)alloc((size_t)2304 * 128 * 4);    // partial m/ls
  unsigned short* sCb = (unsigned short*)alloc((size_t)NROWS * 2176 * 2);  // merged qd|kvd (bf16)

  // fused preprocessing: convert + 5 transposes + bias merge + rope table
  k_prep<<<17417, 256, 0, stream>>>(x, xb, wqd, wqu, wkvd, wkvu, wout,
                                    wqkt, wqut, wkvut, woutt, bqd, bkvd, mbias, rtab);

  // down-projections (merged, bf16 out): sCb = x @ [wqd|wkvd] + bias
  k_gemm_c16<<<32 * 17, 256, 0, stream>>>(xb, wqkt, mbias, sCb, NROWS, 2176, 2048);

  // both rmsnorms in one launch
  k_rmsnorm2<<<2 * NROWS, 256, 0, stream>>>(sCb, qnw, kvnw, qn, kvn);

  // up-projections + krope in one launch
  k_up<<<2816, 256, 0, stream>>>(qn, wqut, bqu, kvn, wkvut, bkvu, sCb, rtab,
                                 qfb, kfb, vtb);

  // attention: deep split-KV (2560 blocks, max 9 iters) + merge
  k_attn<<<2560, 256, 0, stream>>>(qfb, kfb, vtb, ob, pO, pml);
  k_merge<<<768, 256, 0, stream>>>(pO, pml, ob);

  // output projection
  k_gemm<<<32 * 16, 256, 0, stream>>>(ob, woutt, bout, out, NROWS, 2048, 2048);
}

// Round 18
// 391.714 us; speedup vs baseline: 1.5553x; 1.0347x over previous
//
#include <hip/hip_runtime.h>
#include <hip/hip_bf16.h>
#include <math.h>

#define HH 16
#define SS 2048
#define BBATCH 2
#define NROWS 4096   // B*S

typedef __attribute__((ext_vector_type(8))) __bf16 bf16x8;
typedef __attribute__((ext_vector_type(4))) float f32x4;
typedef const __attribute__((address_space(1))) unsigned int* gas1_t;
typedef __attribute__((address_space(3))) unsigned int* las3_t;

__device__ __forceinline__ unsigned short f2bf(float f) {
  unsigned u = __builtin_bit_cast(unsigned, f);
  u += 0x7fffu + ((u >> 16) & 1u);
  return (unsigned short)(u >> 16);
}
__device__ __forceinline__ float bf2f(unsigned short u) {
  return __builtin_bit_cast(float, (unsigned)u << 16);
}

__device__ __forceinline__ void gload16(const void* g, void* l) {
  __builtin_amdgcn_global_load_lds((gas1_t)g, (las3_t)l, 16, 0, 0);
}
__device__ __forceinline__ f32x4 mfma16(bf16x8 a, bf16x8 b, f32x4 c) {
  return __builtin_amdgcn_mfma_f32_16x16x32_bf16(a, b, c, 0, 0, 0);
}

// ---------------- transpose body: W (K,N) f32 -> Wt (Npad,K) bf16 ----------------
__device__ __forceinline__ void transpose_body(const float* __restrict__ W,
                                               unsigned short* __restrict__ Wt,
                                               int K, int N, int Npad,
                                               int bx, int by, float (*tile)[33], int tid) {
  int n0 = bx * 32, k0 = by * 32;
  int tx = tid & 31, ty = tid >> 5;
  for (int i = ty; i < 32; i += 8) {
    int k = k0 + i, n = n0 + tx;
    tile[i][tx] = (k < K && n < N) ? W[(long)k * N + n] : 0.f;
  }
  __syncthreads();
  for (int i = ty; i < 32; i += 8) {
    int n = n0 + i, k = k0 + tx;
    if (n < Npad && k < K) Wt[(long)n * K + k] = f2bf(tile[tx][i]);
  }
}

// ---------------- fused preprocessing: convert + 5 transposes + bias + rope table ----------------
__global__ __launch_bounds__(256) void k_prep(const float* __restrict__ x,
                                              unsigned short* __restrict__ xb,
                                              const float* __restrict__ wqd,
                                              const float* __restrict__ wqu,
                                              const float* __restrict__ wkvd,
                                              const float* __restrict__ wkvu,
                                              const float* __restrict__ wout,
                                              unsigned short* __restrict__ wqkt,
                                              unsigned short* __restrict__ wqut,
                                              unsigned short* __restrict__ wkvut,
                                              unsigned short* __restrict__ woutt,
                                              const float* __restrict__ bqd,
                                              const float* __restrict__ bkvd,
                                              float* __restrict__ mbias,
                                              float2* __restrict__ rtab) {
  __shared__ float tile[32][33];
  int blk = blockIdx.x;
  int tid = threadIdx.x;
  if (blk < 2048) {
    long n4 = (long)NROWS * 2048 / 4;
    for (long i = (long)blk * 256 + tid; i < n4; i += 2048 * 256) {
      float4 v = ((const float4*)x)[i];
      ushort4 o = { f2bf(v.x), f2bf(v.y), f2bf(v.z), f2bf(v.w) };
      ((ushort4*)xb)[i] = o;
    }
  } else if (blk < 5120) {
    int t = blk - 2048;
    transpose_body(wqd, wqkt, 2048, 1536, 1536, t % 48, t / 48, tile, tid);
  } else if (blk < 9728) {
    int t = blk - 5120;
    transpose_body(wqu, wqut, 1536, 3072, 3072, t % 96, t / 96, tile, tid);
  } else if (blk < 11008) {
    int t = blk - 9728;
    transpose_body(wkvd, wqkt + (size_t)1536 * 2048, 2048, 576, 640, t % 20, t / 20, tile, tid);
  } else if (blk < 13056) {
    int t = blk - 11008;
    transpose_body(wkvu, wkvut, 512, 4096, 4096, t % 128, t / 128, tile, tid);
  } else if (blk < 17152) {
    int t = blk - 13056;
    transpose_body(wout, woutt, 2048, 2048, 2048, t % 64, t / 64, tile, tid);
  } else if (blk < 17161) {
    int i = (blk - 17152) * 256 + tid;
    if (i < 2176) mbias[i] = i < 1536 ? bqd[i] : (i < 2112 ? bkvd[i - 1536] : 0.f);
  } else {
    int t = blk - 17161;                    // 256 blocks, 8 s each
    int s = t * 8 + (tid >> 5);
    int i = tid & 31;
    float inv = powf(10000.f, -(float)i / 32.f);
    float ang = (float)s * inv;
    float sn, cs;
    sincosf(ang, &sn, &cs);
    rtab[s * 32 + i] = make_float2(cs, sn);
  }
}

// ---------------- GEMM: C(M,N) f32 = A(M,K)bf16 * Bt(Npad,K)bf16 + bias ----------------
__global__ __launch_bounds__(256) void k_gemm(const unsigned short* __restrict__ A,
                                              const unsigned short* __restrict__ Bt,
                                              const float* __restrict__ bias,
                                              float* __restrict__ C,
                                              int M, int N, int K) {
  __shared__ unsigned short lA[128 * 32];
  __shared__ unsigned short lB[128 * 32];
  int tid = threadIdx.x;
  int wave = tid >> 6, lane = tid & 63;
  int l15 = lane & 15, lhi = lane >> 4;
  int ntn = (N + 127) >> 7;
  int tm = blockIdx.x / ntn, tn = blockIdx.x % ntn;
  long row0 = (long)tm * 128, col0 = (long)tn * 128;
  int wr = wave >> 1, wc = wave & 1;

  const unsigned short* gA = A + (row0 + (tid >> 2)) * K + (tid & 3) * 8;
  const unsigned short* gB = Bt + (col0 + (tid >> 2)) * K + (tid & 3) * 8;
  unsigned short* lA0 = &lA[tid * 8];
  unsigned short* lB0 = &lB[tid * 8];

  f32x4 acc[4][4] = {};
  for (int k0 = 0; k0 < K; k0 += 32) {
    __syncthreads();
    gload16(gA + k0, lA0);
    gload16(gA + (long)64 * K + k0, lA0 + 2048);
    gload16(gB + k0, lB0);
    gload16(gB + (long)64 * K + k0, lB0 + 2048);
    asm volatile("s_waitcnt vmcnt(0)" ::: "memory");
    __syncthreads();
    bf16x8 af[4], bfr[4];
#pragma unroll
    for (int i = 0; i < 4; ++i) {
      af[i]  = *(const bf16x8*)&lA[(wr * 64 + i * 16 + l15) * 32 + lhi * 8];
      bfr[i] = *(const bf16x8*)&lB[(wc * 64 + i * 16 + l15) * 32 + lhi * 8];
    }
#pragma unroll
    for (int i = 0; i < 4; ++i)
#pragma unroll
      for (int j = 0; j < 4; ++j)
        acc[i][j] = mfma16(af[i], bfr[j], acc[i][j]);
  }
#pragma unroll
  for (int i = 0; i < 4; ++i)
#pragma unroll
    for (int j = 0; j < 4; ++j) {
      long r = row0 + wr * 64 + i * 16 + lhi * 4;
      long c = col0 + wc * 64 + j * 16 + l15;
      if (c < N) {
        float bv = bias[c];
#pragma unroll
        for (int rr = 0; rr < 4; ++rr)
          C[(r + rr) * N + c] = acc[i][j][rr] + bv;
      }
    }
}

// ---------------- GEMM with bf16 output (down-proj -> sC bf16) ----------------
__global__ __launch_bounds__(256) void k_gemm_c16(const unsigned short* __restrict__ A,
                                                  const unsigned short* __restrict__ Bt,
                                                  const float* __restrict__ bias,
                                                  unsigned short* __restrict__ C,
                                                  int M, int N, int K) {
  __shared__ unsigned short lA[128 * 32];
  __shared__ unsigned short lB[128 * 32];
  int tid = threadIdx.x;
  int wave = tid >> 6, lane = tid & 63;
  int l15 = lane & 15, lhi = lane >> 4;
  int ntn = (N + 127) >> 7;
  int tm = blockIdx.x / ntn, tn = blockIdx.x % ntn;
  long row0 = (long)tm * 128, col0 = (long)tn * 128;
  int wr = wave >> 1, wc = wave & 1;

  const unsigned short* gA = A + (row0 + (tid >> 2)) * K + (tid & 3) * 8;
  const unsigned short* gB = Bt + (col0 + (tid >> 2)) * K + (tid & 3) * 8;
  unsigned short* lA0 = &lA[tid * 8];
  unsigned short* lB0 = &lB[tid * 8];

  f32x4 acc[4][4] = {};
  for (int k0 = 0; k0 < K; k0 += 32) {
    __syncthreads();
    gload16(gA + k0, lA0);
    gload16(gA + (long)64 * K + k0, lA0 + 2048);
    gload16(gB + k0, lB0);
    gload16(gB + (long)64 * K + k0, lB0 + 2048);
    asm volatile("s_waitcnt vmcnt(0)" ::: "memory");
    __syncthreads();
    bf16x8 af[4], bfr[4];
#pragma unroll
    for (int i = 0; i < 4; ++i) {
      af[i]  = *(const bf16x8*)&lA[(wr * 64 + i * 16 + l15) * 32 + lhi * 8];
      bfr[i] = *(const bf16x8*)&lB[(wc * 64 + i * 16 + l15) * 32 + lhi * 8];
    }
#pragma unroll
    for (int i = 0; i < 4; ++i)
#pragma unroll
      for (int j = 0; j < 4; ++j)
        acc[i][j] = mfma16(af[i], bfr[j], acc[i][j]);
  }
#pragma unroll
  for (int i = 0; i < 4; ++i)
#pragma unroll
    for (int j = 0; j < 4; ++j) {
      long r = row0 + wr * 64 + i * 16 + lhi * 4;
      long c = col0 + wc * 64 + j * 16 + l15;
      if (c < N) {
        float bv = bias[c];
#pragma unroll
        for (int rr = 0; rr < 4; ++rr)
          C[(r + rr) * N + c] = f2bf(acc[i][j][rr] + bv);
      }
    }
}

// ---------------- merged up-projections + krope in ONE launch ----------------
// blocks [0,768): qf GEMM (N=3072, K=1536, fused rope/scale epilogue)
// blocks [768,1792): kv GEMM (N=4096, K=512, fused kf3/vt3 tiled epilogue)
// blocks [1792,2816): krope (4 rows/block, table-based)
__global__ __launch_bounds__(256) void k_up(const unsigned short* __restrict__ qn,
                                            const unsigned short* __restrict__ wqut,
                                            const float* __restrict__ bqu,
                                            const unsigned short* __restrict__ kvn,
                                            const unsigned short* __restrict__ wkvut,
                                            const float* __restrict__ bkvu,
                                            const unsigned short* __restrict__ sCb,
                                            const float2* __restrict__ rtab,
                                            unsigned short* __restrict__ qf,
                                            unsigned short* __restrict__ kf3,
                                            unsigned short* __restrict__ vt3) {
  __shared__ unsigned short smem[16384];   // 32KB
  unsigned short* lA = smem;
  unsigned short* lB = smem + 4096;
  int blk = blockIdx.x;
  int tid = threadIdx.x;
  int wave = tid >> 6, lane = tid & 63;
  int l15 = lane & 15, lhi = lane >> 4;
  int wr = wave >> 1, wc = wave & 1;

  if (blk < 768) {
    // ---- qf GEMM ----
    const int N = 3072, K = 1536;
    int tm = blk / 24, tn = blk % 24;
    long row0 = (long)tm * 128, col0 = (long)tn * 128;
    const unsigned short* gA = qn + (row0 + (tid >> 2)) * K + (tid & 3) * 8;
    const unsigned short* gB = wqut + (col0 + (tid >> 2)) * K + (tid & 3) * 8;
    unsigned short* lA0 = &lA[tid * 8];
    unsigned short* lB0 = &lB[tid * 8];
    f32x4 acc[4][4] = {};
    for (int k0 = 0; k0 < K; k0 += 32) {
      __syncthreads();
      gload16(gA + k0, lA0);
      gload16(gA + (long)64 * K + k0, lA0 + 2048);
      gload16(gB + k0, lB0);
      gload16(gB + (long)64 * K + k0, lB0 + 2048);
      asm volatile("s_waitcnt vmcnt(0)" ::: "memory");
      __syncthreads();
      bf16x8 af[4], bfr[4];
#pragma unroll
      for (int i = 0; i < 4; ++i) {
        af[i]  = *(const bf16x8*)&lA[(wr * 64 + i * 16 + l15) * 32 + lhi * 8];
        bfr[i] = *(const bf16x8*)&lB[(wc * 64 + i * 16 + l15) * 32 + lhi * 8];
      }
#pragma unroll
      for (int i = 0; i < 4; ++i)
#pragma unroll
        for (int j = 0; j < 4; ++j)
          acc[i][j] = mfma16(af[i], bfr[j], acc[i][j]);
    }
    const float scq = 0.07216878364870322f * 1.4426950408889634f;  // 192^-0.5 * log2(e)
    int base = (int)col0 + wc * 64;
    int h = base / 192;
    int m192 = base - h * 192;   // 0, 64, or 128 (wave-uniform)
    float bv[4];
#pragma unroll
    for (int j = 0; j < 4; ++j) bv[j] = bqu[base + j * 16 + l15];
#pragma unroll
    for (int i = 0; i < 4; ++i) {
#pragma unroll
      for (int rr = 0; rr < 4; ++rr) {
        long r = row0 + wr * 64 + i * 16 + lhi * 4 + rr;
        int s = (int)(r & 2047), b = (int)(r >> 11);
        unsigned short* dst = qf + (((long)(b * HH + h)) * SS + s) * 192;
        if (m192 < 128) {
#pragma unroll
          for (int j = 0; j < 4; ++j)
            dst[m192 + j * 16 + l15] = f2bf((acc[i][j][rr] + bv[j]) * scq);
        } else {
#pragma unroll
          for (int j = 0; j < 2; ++j) {
            int ifq = j * 16 + l15;
            float2 cs = rtab[s * 32 + ifq];
            float v1 = acc[i][j][rr] + bv[j];
            float v2 = acc[i][j + 2][rr] + bv[j + 2];
            dst[128 + ifq] = f2bf((v1 * cs.x - v2 * cs.y) * scq);
            dst[160 + ifq] = f2bf((v2 * cs.x + v1 * cs.y) * scq);
          }
        }
      }
    }
  } else if (blk < 1792) {
    // ---- kv GEMM with tiled epilogue ----
    const int N = 4096, K = 512;
    int b2 = blk - 768;
    int tm = b2 / 32, tn = b2 % 32;
    long row0 = (long)tm * 128, col0 = (long)tn * 128;
    const unsigned short* gA = kvn + (row0 + (tid >> 2)) * K + (tid & 3) * 8;
    const unsigned short* gB = wkvut + (col0 + (tid >> 2)) * K + (tid & 3) * 8;
    unsigned short* lA0 = &lA[tid * 8];
    unsigned short* lB0 = &lB[tid * 8];
    f32x4 acc[4][4] = {};
    for (int k0 = 0; k0 < K; k0 += 32) {
      __syncthreads();
      gload16(gA + k0, lA0);
      gload16(gA + (long)64 * K + k0, lA0 + 2048);
      gload16(gB + k0, lB0);
      gload16(gB + (long)64 * K + k0, lB0 + 2048);
      asm volatile("s_waitcnt vmcnt(0)" ::: "memory");
      __syncthreads();
      bf16x8 af[4], bfr[4];
#pragma unroll
      for (int i = 0; i < 4; ++i) {
        af[i]  = *(const bf16x8*)&lA[(wr * 64 + i * 16 + l15) * 32 + lhi * 8];
        bfr[i] = *(const bf16x8*)&lB[(wc * 64 + i * 16 + l15) * 32 + lhi * 8];
      }
#pragma unroll
      for (int i = 0; i < 4; ++i)
#pragma unroll
        for (int j = 0; j < 4; ++j)
          acc[i][j] = mfma16(af[i], bfr[j], acc[i][j]);
    }
    int base = (int)col0 + wc * 64;
    int h = base >> 8;
    bool isv = (base & 255) >= 128;   // block-uniform (tn parity)
    float bv[4];
#pragma unroll
    for (int j = 0; j < 4; ++j) bv[j] = bkvu[base + j * 16 + l15];
    int b = (int)(row0 >> 11);
    long bh = (long)b * HH + h;
    int lrb = wr * 64;
    __syncthreads();
    if (isv) {
#pragma unroll
      for (int i = 0; i < 4; ++i) {
        int lr = lrb + i * 16 + lhi * 4;
#pragma unroll
        for (int j = 0; j < 4; ++j) {
          int lc = wc * 64 + j * 16 + l15;
          ushort4 pk = { f2bf(acc[i][j][0] + bv[j]), f2bf(acc[i][j][1] + bv[j]),
                         f2bf(acc[i][j][2] + bv[j]), f2bf(acc[i][j][3] + bv[j]) };
          *(ushort4*)&smem[((lr >> 5) << 12) + lc * 32 + (lr & 31)] = pk;
        }
      }
      __syncthreads();
      long dst0 = (bh * 64 + ((row0 & 2047) >> 5)) * 4096;
#pragma unroll
      for (int p = 0; p < 8; ++p) {
        int e = p * 256 + tid;
        *(uint4*)&vt3[dst0 + e * 8] = *(uint4*)&smem[e * 8];
      }
    } else {
#pragma unroll
      for (int i = 0; i < 4; ++i) {
        int lr0 = lrb + i * 16 + lhi * 4;
#pragma unroll
        for (int j = 0; j < 4; ++j) {
          int c = (base & 255) + j * 16 + l15;   // 0..127
          int tbase = ((lr0 >> 4) << 11) + ((c >> 5) << 9) + (((c >> 3) & 3) << 7) + (c & 7);
#pragma unroll
          for (int rr = 0; rr < 4; ++rr)
            smem[tbase + ((lr0 + rr) & 15) * 8] = f2bf(acc[i][j][rr] + bv[j]);
        }
      }
      __syncthreads();
      long kb3 = (bh * 128 + ((row0 & 2047) >> 4)) * 3072;
#pragma unroll
      for (int p = 0; p < 8; ++p) {
        int e = p * 256 + tid;
        int tile = e >> 6;
        int off = (e & 63) * 8;
        long dst = kb3 + ((long)(tile >> 2) * 6 + (tile & 3)) * 512 + off;
        *(uint4*)&kf3[dst] = *(uint4*)&smem[tile * 512 + off];
      }
    }
  } else {
    // ---- krope: 4 rows per block ----
    int t = blk - 1792;
    int bs = t * 4 + (tid >> 6);
    int s = bs & (SS - 1), b = bs >> 11;
    const unsigned short* src = sCb + (long)bs * 2176 + 2048;
    int i = lane & 31;
    float2 cs = rtab[s * 32 + i];
    float t1 = bf2f(src[i]), t2 = bf2f(src[32 + i]);
    float v = (lane < 32) ? (t1 * cs.x - t2 * cs.y) : (t2 * cs.x + t1 * cs.y);
    unsigned short bv = f2bf(v);
    int d = 128 + lane;
    long inner = (long)(d >> 5) * 512 + ((d >> 3) & 3) * 128 + (s & 15) * 8 + (d & 7);
#pragma unroll
    for (int h = 0; h < HH; ++h) {
      long kblk = ((long)(b * HH + h) * 128 + (s >> 4)) * 6;
      kf3[kblk * 512 + inner] = bv;
    }
  }
}

// ---------------- merged RMSNorm (q rows then kv rows): bf16 -> bf16 ----------------
__global__ __launch_bounds__(256) void k_rmsnorm2(const unsigned short* __restrict__ sC,
                                                  const float* __restrict__ qnw,
                                                  const float* __restrict__ kvnw,
                                                  unsigned short* __restrict__ qn,
                                                  unsigned short* __restrict__ kvn) {
  int blk = blockIdx.x;
  long row;
  const unsigned short* x;
  const float* w;
  unsigned short* y;
  int L;
  if (blk < NROWS) {
    row = blk; x = sC + row * 2176; w = qnw; y = qn + row * 1536; L = 1536;
  } else {
    row = blk - NROWS; x = sC + row * 2176 + 1536; w = kvnw; y = kvn + row * 512; L = 512;
  }
  float ss = 0.f;
  int n4 = L >> 2;
  for (int i = threadIdx.x; i < n4; i += 256) {
    ushort4 v = ((const ushort4*)x)[i];
    float a = bf2f(v.x), bb = bf2f(v.y), c = bf2f(v.z), d = bf2f(v.w);
    ss += a * a + bb * bb + c * c + d * d;
  }
  for (int off = 32; off > 0; off >>= 1) ss += __shfl_xor(ss, off);
  __shared__ float sb[4];
  if ((threadIdx.x & 63) == 0) sb[threadIdx.x >> 6] = ss;
  __syncthreads();
  float scale = rsqrtf((sb[0] + sb[1] + sb[2] + sb[3]) / (float)L + 1e-6f);
  for (int i = threadIdx.x; i < L; i += 256)
    y[i] = f2bf(bf2f(x[i]) * scale * w[i]);
}

// ---------------- flash attention: deep split-KV (round-15 best config) ----------------
__global__ __launch_bounds__(256, 4) void k_attn(const unsigned short* __restrict__ qf,
                                                 const unsigned short* __restrict__ kf3,
                                                 const unsigned short* __restrict__ vt3,
                                                 unsigned short* __restrict__ o,
                                                 float* __restrict__ pO,
                                                 float* __restrict__ pml) {
  __shared__ unsigned short kbuf[64 * 192];     // 24KB, single buffer
  __shared__ unsigned short pbuf[4][16 * 72];   // per-wave P transpose buffer (stride 72)
  int tid = threadIdx.x;
  int wave = tid >> 6, lane = tid & 63;
  int l15 = lane & 15, lhi = lane >> 4;
  int idx = blockIdx.x;
  int rp = idx >> 5, bh = idx & 31;
  int qt, part, np;
  if (rp < 32)      { qt = 24 + (rp >> 2); part = rp & 3; np = 4; }
  else if (rp < 56) { int r = rp - 32; qt = 16 + r / 3; part = r % 3; np = 3; }
  else if (rp < 72) { int r = rp - 56; qt = 8 + (r >> 1); part = r & 1; np = 2; }
  else              { qt = 79 - rp; part = 0; np = 1; }
  int nt = qt + 1;
  int t0 = nt * part / np, t1 = nt * (part + 1) / np;
  bool dodiag = (part == np - 1);
  int item;
  if (np == 1) item = -1;
  else {
    int base = (qt < 16) ? (qt - 8) * 2 : (qt < 24) ? 16 + (qt - 16) * 3 : 40 + (qt - 24) * 4;
    item = bh * 72 + base + part;
  }
  int b = bh >> 4, h = bh & 15;
  int q0 = qt * 64;
  const char* kbase = (const char*)(kf3 + (long)bh * 128 * 3072);
  const unsigned short* vfrag0 = vt3 + (long)bh * 64 * 4096 + l15 * 32 + lhi * 8;
  const unsigned short* kread = kbuf + lane * 8;
  unsigned psel = 0x07060302u;   // v_perm selector: {s0.hi16, s1.hi16}

  // prologue: stage K tile t0
  {
    const char* src = kbase + (long)t0 * 24576 + tid * 16;
    char* dst = (char*)kbuf + tid * 16;
#pragma unroll
    for (int p = 0; p < 6; ++p) gload16(src + p * 4096, dst + p * 4096);
  }

  // Q fragments (B-operand) — loads overlap stage latency
  const unsigned short* Qb = qf + ((long)bh * SS + q0 + wave * 16 + l15) * 192 + lhi * 8;
  bf16x8 qfr[6];
#pragma unroll
  for (int ks = 0; ks < 6; ++ks) qfr[ks] = *(const bf16x8*)(Qb + ks * 32);

  float m = -3e38f, ls = 0.f;
  f32x4 acc[8] = {};
  int qin = wave * 16 + l15;

  for (int t = t0; t < t1; ++t) {
    asm volatile("s_waitcnt vmcnt(0)" ::: "memory");
    __builtin_amdgcn_s_barrier();
    __builtin_amdgcn_sched_barrier(0);

    // QK^T (swapped): sc[nf] rows k=nf*16+lhi*4+j, col q=l15; conflict-free LDS reads
    f32x4 sc[4] = {};
    __builtin_amdgcn_s_setprio(1);
#pragma unroll
    for (int ks = 0; ks < 6; ++ks) {
      bf16x8 kfr[4];
#pragma unroll
      for (int nf = 0; nf < 4; ++nf)
        kfr[nf] = *(const bf16x8*)&kread[(nf * 6 + ks) * 512];
#pragma unroll
      for (int nf = 0; nf < 4; ++nf)
        sc[nf] = mfma16(kfr[nf], qfr[ks], sc[nf]);
    }
    __builtin_amdgcn_s_setprio(0);
    __builtin_amdgcn_sched_barrier(0);
    __builtin_amdgcn_s_barrier();          // all waves done reading kbuf
    __builtin_amdgcn_sched_barrier(0);

    // V batch 0 issue (softmax covers latency)
    const unsigned short* vtb = vfrag0 + (long)t * 8192;
    bf16x8 v0[8];
#pragma unroll
    for (int nf = 0; nf < 8; ++nf) v0[nf] = *(const bf16x8*)(vtb + nf * 512);
    __builtin_amdgcn_sched_barrier(0);

    // stage K tile t+1 (WAR barrier above; hides under softmax+PV)
    if (t + 1 < t1) {
      const char* src = kbase + (long)(t + 1) * 24576 + tid * 16;
      char* dst = (char*)kbuf + tid * 16;
#pragma unroll
      for (int p = 0; p < 6; ++p) gload16(src + p * 4096, dst + p * 4096);
    }

    // online softmax, lane-local over k
    bool diag = dodiag && (t == t1 - 1);
    float mnf[4];
#pragma unroll
    for (int nf = 0; nf < 4; ++nf) {
      if (diag) {
#pragma unroll
        for (int jj = 0; jj < 4; ++jj) {
          int kin = nf * 16 + lhi * 4 + jj;
          if (kin > qin) sc[nf][jj] = -3e38f;
        }
      }
      mnf[nf] = fmaxf(fmaxf(sc[nf][0], sc[nf][1]), fmaxf(sc[nf][2], sc[nf][3]));
    }
    float mx = fmaxf(fmaxf(mnf[0], mnf[1]), fmaxf(mnf[2], mnf[3]));
    mx = fmaxf(mx, __shfl_xor(mx, 16));
    mx = fmaxf(mx, __shfl_xor(mx, 32));
    if (!__all(mx <= m + 8.f)) {      // defer-rescale (exp2 domain, THR=8)
      float mn = fmaxf(m, mx);
      float alpha = exp2f(m - mn);
      m = mn;
      ls *= alpha;
#pragma unroll
      for (int nf = 0; nf < 8; ++nf)
#pragma unroll
        for (int jj = 0; jj < 4; ++jj) acc[nf][jj] *= alpha;
    }
    float pnf[4];
#pragma unroll
    for (int nf = 0; nf < 4; ++nf) {
      float e0 = exp2f(sc[nf][0] - m), e1 = exp2f(sc[nf][1] - m);
      float e2 = exp2f(sc[nf][2] - m), e3 = exp2f(sc[nf][3] - m);
      pnf[nf] = (e0 + e1) + (e2 + e3);
      unsigned lo, hi;   // pack 2 truncated bf16 per v_perm (P in [0,256): trunc err <0.4%)
      asm("v_perm_b32 %0, %1, %2, %3" : "=v"(lo) : "v"(e1), "v"(e0), "s"(psel));
      asm("v_perm_b32 %0, %1, %2, %3" : "=v"(hi) : "v"(e3), "v"(e2), "s"(psel));
      uint2 pk = { lo, hi };
      *(uint2*)&pbuf[wave][l15 * 72 + nf * 16 + lhi * 4] = pk;
    }
    float ps = (pnf[0] + pnf[1]) + (pnf[2] + pnf[3]);
    ps += __shfl_xor(ps, 16);
    ps += __shfl_xor(ps, 32);
    ls += ps;

    // PV kk=0 with v0
    {
      bf16x8 pf = *(const bf16x8*)&pbuf[wave][l15 * 72 + lhi * 8];
      __builtin_amdgcn_s_setprio(1);
#pragma unroll
      for (int nf = 0; nf < 8; ++nf) acc[nf] = mfma16(v0[nf], pf, acc[nf]);
      __builtin_amdgcn_s_setprio(0);
    }
    // V batch 1 (reuses v0's registers), then PV kk=1
    bf16x8 v1[8];
#pragma unroll
    for (int nf = 0; nf < 8; ++nf) v1[nf] = *(const bf16x8*)(vtb + 4096 + nf * 512);
    {
      bf16x8 pf = *(const bf16x8*)&pbuf[wave][l15 * 72 + 32 + lhi * 8];
      __builtin_amdgcn_s_setprio(1);
#pragma unroll
      for (int nf = 0; nf < 8; ++nf) acc[nf] = mfma16(v1[nf], pf, acc[nf]);
      __builtin_amdgcn_s_setprio(0);
    }
  }

  int qloc = wave * 16 + l15;
  if (item < 0) {
    // single: normalize + write o (row q=l15, d = nf*16+lhi*4+j)
    float invl = 1.f / ls;
    long orow = (long)b * SS + q0 + qloc;
#pragma unroll
    for (int nf = 0; nf < 8; ++nf) {
      ushort4 ov = { f2bf(acc[nf][0] * invl), f2bf(acc[nf][1] * invl),
                     f2bf(acc[nf][2] * invl), f2bf(acc[nf][3] * invl) };
      *(ushort4*)&o[orow * 2048 + h * 128 + nf * 16 + lhi * 4] = ov;
    }
  } else {
    // split: write unnormalized partials
    float* po = pO + (long)item * 8192 + qloc * 128;
#pragma unroll
    for (int nf = 0; nf < 8; ++nf)
      *(float4*)&po[nf * 16 + lhi * 4] = __builtin_bit_cast(float4, acc[nf]);
    if (lhi == 0) {
      pml[(long)item * 128 + qloc * 2] = m;
      pml[(long)item * 128 + qloc * 2 + 1] = ls;
    }
  }
}

// ---------------- merge split-KV partials (2-4 parts) -> o ----------------
__global__ __launch_bounds__(256) void k_merge(const float* __restrict__ pO,
                                               const float* __restrict__ pml,
                                               unsigned short* __restrict__ o) {
  int g = blockIdx.x;              // bh*24 + (qt-8)
  int bh = g / 24, qt = (g % 24) + 8;
  int b = bh >> 4, h = bh & 15;
  int q0 = qt * 64;
  int np = qt < 16 ? 2 : (qt < 24 ? 3 : 4);
  int base = (qt < 16) ? (qt - 8) * 2 : (qt < 24) ? 16 + (qt - 16) * 3 : 40 + (qt - 24) * 4;
  long i0 = (long)bh * 72 + base;
  __shared__ float wts[4][64];
  int tid = threadIdx.x;
  if (tid < 64) {
    float mp0 = -3e38f, mp1 = -3e38f, mp2 = -3e38f, mp3 = -3e38f;
    float lp0 = 0.f, lp1 = 0.f, lp2 = 0.f, lp3 = 0.f;
    mp0 = pml[(i0 + 0) * 128 + tid * 2]; lp0 = pml[(i0 + 0) * 128 + tid * 2 + 1];
    mp1 = pml[(i0 + 1) * 128 + tid * 2]; lp1 = pml[(i0 + 1) * 128 + tid * 2 + 1];
    if (np > 2) { mp2 = pml[(i0 + 2) * 128 + tid * 2]; lp2 = pml[(i0 + 2) * 128 + tid * 2 + 1]; }
    if (np > 3) { mp3 = pml[(i0 + 3) * 128 + tid * 2]; lp3 = pml[(i0 + 3) * 128 + tid * 2 + 1]; }
    float mm = fmaxf(fmaxf(mp0, mp1), fmaxf(mp2, mp3));
    float w0 = exp2f(mp0 - mm), w1 = exp2f(mp1 - mm);
    float w2 = (np > 2) ? exp2f(mp2 - mm) : 0.f;
    float w3 = (np > 3) ? exp2f(mp3 - mm) : 0.f;
    float inv = 1.f / (lp0 * w0 + lp1 * w1 + lp2 * w2 + lp3 * w3);
    wts[0][tid] = w0 * inv; wts[1][tid] = w1 * inv;
    wts[2][tid] = w2 * inv; wts[3][tid] = w3 * inv;
  }
  __syncthreads();
#pragma unroll
  for (int pp = 0; pp < 8; ++pp) {
    int e = pp * 256 + tid;          // float4 units: 2048 total
    int q = e >> 5, d4 = (e & 31) * 4;
    float4 s = { 0.f, 0.f, 0.f, 0.f };
#pragma unroll
    for (int p = 0; p < 4; ++p) {
      if (p < np) {
        float4 a = *(const float4*)&pO[(i0 + p) * 8192 + q * 128 + d4];
        float w = wts[p][q];
        s.x += a.x * w; s.y += a.y * w; s.z += a.z * w; s.w += a.w * w;
      }
    }
    ushort4 ov = { f2bf(s.x), f2bf(s.y), f2bf(s.z), f2bf(s.w) };
    *(ushort4*)&o[((long)b * SS + q0 + q) * 2048 + h * 128 + d4] = ov;
  }
}

extern "C" void kernel_launch(void* const* d_in, const int* in_sizes, int n_in,
                              void* d_out, int out_size, void* d_ws, size_t ws_size,
                              hipStream_t stream) {
  const float* x    = (const float*)d_in[0];
  const float* wqd  = (const float*)d_in[1];
  const float* bqd  = (const float*)d_in[2];
  const float* qnw  = (const float*)d_in[3];
  const float* wqu  = (const float*)d_in[4];
  const float* bqu  = (const float*)d_in[5];
  const float* wkvd = (const float*)d_in[6];
  const float* bkvd = (const float*)d_in[7];
  const float* kvnw = (const float*)d_in[8];
  const float* wkvu = (const float*)d_in[9];
  const float* bkvu = (const float*)d_in[10];
  const float* wout = (const float*)d_in[11];
  const float* bout = (const float*)d_in[12];
  float* out = (float*)d_out;

  char* ws = (char*)d_ws;
  size_t off = 0;
  auto alloc = [&](size_t sz) {
    char* p = ws + off;
    off += (sz + 255) & ~(size_t)255;
    return p;
  };
  unsigned short* xb    = (unsigned short*)alloc((size_t)NROWS * 2048 * 2);
  unsigned short* wqkt  = (unsigned short*)alloc((size_t)2176 * 2048 * 2);  // [wqd;wkvd]^T
  unsigned short* wqut  = (unsigned short*)alloc((size_t)3072 * 1536 * 2);
  unsigned short* wkvut = (unsigned short*)alloc((size_t)4096 * 512 * 2);
  unsigned short* woutt = (unsigned short*)alloc((size_t)2048 * 2048 * 2);
  unsigned short* qn    = (unsigned short*)alloc((size_t)NROWS * 1536 * 2);
  unsigned short* kvn   = (unsigned short*)alloc((size_t)NROWS * 512 * 2);
  unsigned short* qfb   = (unsigned short*)alloc((size_t)32 * SS * 192 * 2);
  unsigned short* kfb   = (unsigned short*)alloc((size_t)32 * SS * 192 * 2);   // kf3 tiled
  unsigned short* vtb   = (unsigned short*)alloc((size_t)32 * 128 * SS * 2);   // vt3 tiled
  unsigned short* ob    = (unsigned short*)alloc((size_t)NROWS * 2048 * 2);
  float*  mbias = (float*)alloc((size_t)2176 * 4);
  float2* rtab  = (float2*)alloc((size_t)SS * 32 * 8);
  float*  pO    = (float*)alloc((size_t)2304 * 8192 * 4);   // 75.5 MB partial O
  float*  pml   = (float*)alloc((size_t)2304 * 128 * 4);    // partial m/ls
  unsigned short* sCb = (unsigned short*)alloc((size_t)NROWS * 2176 * 2);  // merged qd|kvd (bf16)

  // fused preprocessing: convert + 5 transposes + bias merge + rope table
  k_prep<<<17417, 256, 0, stream>>>(x, xb, wqd, wqu, wkvd, wkvu, wout,
                                    wqkt, wqut, wkvut, woutt, bqd, bkvd, mbias, rtab);

  // down-projections (merged, bf16 out): sCb = x @ [wqd|wkvd] + bias
  k_gemm_c16<<<32 * 17, 256, 0, stream>>>(xb, wqkt, mbias, sCb, NROWS, 2176, 2048);

  // both rmsnorms in one launch
  k_rmsnorm2<<<2 * NROWS, 256, 0, stream>>>(sCb, qnw, kvnw, qn, kvn);

  // up-projections + krope in one launch
  k_up<<<2816, 256, 0, stream>>>(qn, wqut, bqu, kvn, wkvut, bkvu, sCb, rtab,
                                 qfb, kfb, vtb);

  // attention: deep split-KV (2560 blocks, max 9 iters) + merge
  k_attn<<<2560, 256, 0, stream>>>(qfb, kfb, vtb, ob, pO, pml);
  k_merge<<<768, 256, 0, stream>>>(pO, pml, ob);

  // output projection
  k_gemm<<<32 * 16, 256, 0, stream>>>(ob, woutt, bout, out, NROWS, 2048, 2048);
}

// Round 19
// 345.959 us; speedup vs baseline: 1.7610x; 1.1323x over previous
//
#include <hip/hip_runtime.h>
#include <hip/hip_bf16.h>
#include <math.h>

#define HH 16
#define SS 2048
#define BBATCH 2
#define NROWS 4096   // B*S

typedef __attribute__((ext_vector_type(8))) __bf16 bf16x8;
typedef __attribute__((ext_vector_type(4))) float f32x4;
typedef const __attribute__((address_space(1))) unsigned int* gas1_t;
typedef __attribute__((address_space(3))) unsigned int* las3_t;

__device__ __forceinline__ unsigned short f2bf(float f) {
  unsigned u = __builtin_bit_cast(unsigned, f);
  u += 0x7fffu + ((u >> 16) & 1u);
  return (unsigned short)(u >> 16);
}
__device__ __forceinline__ float bf2f(unsigned short u) {
  return __builtin_bit_cast(float, (unsigned)u << 16);
}

__device__ __forceinline__ void gload16(const void* g, void* l) {
  __builtin_amdgcn_global_load_lds((gas1_t)g, (las3_t)l, 16, 0, 0);
}
__device__ __forceinline__ f32x4 mfma16(bf16x8 a, bf16x8 b, f32x4 c) {
  return __builtin_amdgcn_mfma_f32_16x16x32_bf16(a, b, c, 0, 0, 0);
}

// ---------------- shared BK=64 GEMM core (128x128 tile, 4 waves) ----------------
// Staging: global source pre-swizzled per granule (cg ^= row&7), LDS dest linear
// (rule: swizzle both sides or neither with global_load_lds). Reads apply the
// same XOR -> 8-way max bank aliasing (parity with the BK=32 layout) while the
// barrier/vmcnt-drain count per 64 K-elements is halved.
__device__ __forceinline__ void gemm_core64(const unsigned short* __restrict__ A,
                                            const unsigned short* __restrict__ Bt,
                                            int K, long row0, long col0, int tid,
                                            unsigned short* lA, unsigned short* lB,
                                            f32x4 (*acc)[4]) {
  int wave = tid >> 6, lane = tid & 63;
  int l15 = lane & 15, lhi = lane >> 4;
  int wr = wave >> 1, wc = wave & 1;
  int trow = tid >> 3, tcg = tid & 7;
  const unsigned short* gA = A + (row0 + trow) * K + ((tcg ^ (trow & 7)) * 8);
  const unsigned short* gB = Bt + (col0 + trow) * K + ((tcg ^ (trow & 7)) * 8);
  unsigned short* lA0 = &lA[tid * 8];
  unsigned short* lB0 = &lB[tid * 8];
  for (int k0 = 0; k0 < K; k0 += 64) {
    __syncthreads();
#pragma unroll
    for (int p = 0; p < 4; ++p) {
      gload16(gA + (long)p * 32 * K + k0, lA0 + p * 2048);
      gload16(gB + (long)p * 32 * K + k0, lB0 + p * 2048);
    }
    asm volatile("s_waitcnt vmcnt(0)" ::: "memory");
    __syncthreads();
#pragma unroll
    for (int kk = 0; kk < 2; ++kk) {
      bf16x8 af[4], bfr[4];
#pragma unroll
      for (int i = 0; i < 4; ++i) {
        int rA = wr * 64 + i * 16 + l15;
        int rB = wc * 64 + i * 16 + l15;
        af[i]  = *(const bf16x8*)&lA[rA * 64 + (((kk * 4 + lhi) ^ (rA & 7)) * 8)];
        bfr[i] = *(const bf16x8*)&lB[rB * 64 + (((kk * 4 + lhi) ^ (rB & 7)) * 8)];
      }
#pragma unroll
      for (int i = 0; i < 4; ++i)
#pragma unroll
        for (int j = 0; j < 4; ++j)
          acc[i][j] = mfma16(af[i], bfr[j], acc[i][j]);
    }
  }
}

// ---------------- transpose body: W (K,N) f32 -> Wt (Npad,K) bf16 ----------------
__device__ __forceinline__ void transpose_body(const float* __restrict__ W,
                                               unsigned short* __restrict__ Wt,
                                               int K, int N, int Npad,
                                               int bx, int by, float (*tile)[33], int tid) {
  int n0 = bx * 32, k0 = by * 32;
  int tx = tid & 31, ty = tid >> 5;
  for (int i = ty; i < 32; i += 8) {
    int k = k0 + i, n = n0 + tx;
    tile[i][tx] = (k < K && n < N) ? W[(long)k * N + n] : 0.f;
  }
  __syncthreads();
  for (int i = ty; i < 32; i += 8) {
    int n = n0 + i, k = k0 + tx;
    if (n < Npad && k < K) Wt[(long)n * K + k] = f2bf(tile[tx][i]);
  }
}

// ---------------- fused preprocessing: convert + 5 transposes + bias + rope table ----------------
__global__ __launch_bounds__(256) void k_prep(const float* __restrict__ x,
                                              unsigned short* __restrict__ xb,
                                              const float* __restrict__ wqd,
                                              const float* __restrict__ wqu,
                                              const float* __restrict__ wkvd,
                                              const float* __restrict__ wkvu,
                                              const float* __restrict__ wout,
                                              unsigned short* __restrict__ wqkt,
                                              unsigned short* __restrict__ wqut,
                                              unsigned short* __restrict__ wkvut,
                                              unsigned short* __restrict__ woutt,
                                              const float* __restrict__ bqd,
                                              const float* __restrict__ bkvd,
                                              float* __restrict__ mbias,
                                              float2* __restrict__ rtab) {
  __shared__ float tile[32][33];
  int blk = blockIdx.x;
  int tid = threadIdx.x;
  if (blk < 2048) {
    long n4 = (long)NROWS * 2048 / 4;
    for (long i = (long)blk * 256 + tid; i < n4; i += 2048 * 256) {
      float4 v = ((const float4*)x)[i];
      ushort4 o = { f2bf(v.x), f2bf(v.y), f2bf(v.z), f2bf(v.w) };
      ((ushort4*)xb)[i] = o;
    }
  } else if (blk < 5120) {
    int t = blk - 2048;
    transpose_body(wqd, wqkt, 2048, 1536, 1536, t % 48, t / 48, tile, tid);
  } else if (blk < 9728) {
    int t = blk - 5120;
    transpose_body(wqu, wqut, 1536, 3072, 3072, t % 96, t / 96, tile, tid);
  } else if (blk < 11008) {
    int t = blk - 9728;
    transpose_body(wkvd, wqkt + (size_t)1536 * 2048, 2048, 576, 640, t % 20, t / 20, tile, tid);
  } else if (blk < 13056) {
    int t = blk - 11008;
    transpose_body(wkvu, wkvut, 512, 4096, 4096, t % 128, t / 128, tile, tid);
  } else if (blk < 17152) {
    int t = blk - 13056;
    transpose_body(wout, woutt, 2048, 2048, 2048, t % 64, t / 64, tile, tid);
  } else if (blk < 17161) {
    int i = (blk - 17152) * 256 + tid;
    if (i < 2176) mbias[i] = i < 1536 ? bqd[i] : (i < 2112 ? bkvd[i - 1536] : 0.f);
  } else {
    int t = blk - 17161;                    // 256 blocks, 8 s each
    int s = t * 8 + (tid >> 5);
    int i = tid & 31;
    float inv = powf(10000.f, -(float)i / 32.f);
    float ang = (float)s * inv;
    float sn, cs;
    sincosf(ang, &sn, &cs);
    rtab[s * 32 + i] = make_float2(cs, sn);
  }
}

// ---------------- GEMM: C(M,N) f32 = A(M,K)bf16 * Bt(Npad,K)bf16 + bias ----------------
__global__ __launch_bounds__(256) void k_gemm(const unsigned short* __restrict__ A,
                                              const unsigned short* __restrict__ Bt,
                                              const float* __restrict__ bias,
                                              float* __restrict__ C,
                                              int M, int N, int K) {
  __shared__ unsigned short lA[128 * 64];
  __shared__ unsigned short lB[128 * 64];
  int tid = threadIdx.x;
  int wave = tid >> 6, lane = tid & 63;
  int l15 = lane & 15, lhi = lane >> 4;
  int ntn = (N + 127) >> 7;
  int tm = blockIdx.x / ntn, tn = blockIdx.x % ntn;
  long row0 = (long)tm * 128, col0 = (long)tn * 128;
  int wr = wave >> 1, wc = wave & 1;

  f32x4 acc[4][4] = {};
  gemm_core64(A, Bt, K, row0, col0, tid, lA, lB, acc);

#pragma unroll
  for (int i = 0; i < 4; ++i)
#pragma unroll
    for (int j = 0; j < 4; ++j) {
      long r = row0 + wr * 64 + i * 16 + lhi * 4;
      long c = col0 + wc * 64 + j * 16 + l15;
      if (c < N) {
        float bv = bias[c];
#pragma unroll
        for (int rr = 0; rr < 4; ++rr)
          C[(r + rr) * N + c] = acc[i][j][rr] + bv;
      }
    }
}

// ---------------- GEMM with bf16 output (down-proj -> sC bf16) ----------------
__global__ __launch_bounds__(256) void k_gemm_c16(const unsigned short* __restrict__ A,
                                                  const unsigned short* __restrict__ Bt,
                                                  const float* __restrict__ bias,
                                                  unsigned short* __restrict__ C,
                                                  int M, int N, int K) {
  __shared__ unsigned short lA[128 * 64];
  __shared__ unsigned short lB[128 * 64];
  int tid = threadIdx.x;
  int wave = tid >> 6, lane = tid & 63;
  int l15 = lane & 15, lhi = lane >> 4;
  int ntn = (N + 127) >> 7;
  int tm = blockIdx.x / ntn, tn = blockIdx.x % ntn;
  long row0 = (long)tm * 128, col0 = (long)tn * 128;
  int wr = wave >> 1, wc = wave & 1;

  f32x4 acc[4][4] = {};
  gemm_core64(A, Bt, K, row0, col0, tid, lA, lB, acc);

#pragma unroll
  for (int i = 0; i < 4; ++i)
#pragma unroll
    for (int j = 0; j < 4; ++j) {
      long r = row0 + wr * 64 + i * 16 + lhi * 4;
      long c = col0 + wc * 64 + j * 16 + l15;
      if (c < N) {
        float bv = bias[c];
#pragma unroll
        for (int rr = 0; rr < 4; ++rr)
          C[(r + rr) * N + c] = f2bf(acc[i][j][rr] + bv);
      }
    }
}

// ---------------- merged up-projections + krope in ONE launch ----------------
// blocks [0,768): qf GEMM (N=3072, K=1536, fused rope/scale epilogue)
// blocks [768,1792): kv GEMM (N=4096, K=512, fused kf3/vt3 tiled epilogue)
// blocks [1792,2816): krope (4 rows/block, table-based)
__global__ __launch_bounds__(256) void k_up(const unsigned short* __restrict__ qn,
                                            const unsigned short* __restrict__ wqut,
                                            const float* __restrict__ bqu,
                                            const unsigned short* __restrict__ kvn,
                                            const unsigned short* __restrict__ wkvut,
                                            const float* __restrict__ bkvu,
                                            const unsigned short* __restrict__ sCb,
                                            const float2* __restrict__ rtab,
                                            unsigned short* __restrict__ qf,
                                            unsigned short* __restrict__ kf3,
                                            unsigned short* __restrict__ vt3) {
  __shared__ unsigned short smem[16384];   // 32KB: lA/lB in loop, stage in epilogue
  unsigned short* lA = smem;
  unsigned short* lB = smem + 8192;
  int blk = blockIdx.x;
  int tid = threadIdx.x;
  int wave = tid >> 6, lane = tid & 63;
  int l15 = lane & 15, lhi = lane >> 4;
  int wr = wave >> 1, wc = wave & 1;

  if (blk < 768) {
    // ---- qf GEMM ----
    const int K = 1536;
    int tm = blk / 24, tn = blk % 24;
    long row0 = (long)tm * 128, col0 = (long)tn * 128;
    f32x4 acc[4][4] = {};
    gemm_core64(qn, wqut, K, row0, col0, tid, lA, lB, acc);

    const float scq = 0.07216878364870322f * 1.4426950408889634f;  // 192^-0.5 * log2(e)
    int base = (int)col0 + wc * 64;
    int h = base / 192;
    int m192 = base - h * 192;   // 0, 64, or 128 (wave-uniform)
    float bv[4];
#pragma unroll
    for (int j = 0; j < 4; ++j) bv[j] = bqu[base + j * 16 + l15];
#pragma unroll
    for (int i = 0; i < 4; ++i) {
#pragma unroll
      for (int rr = 0; rr < 4; ++rr) {
        long r = row0 + wr * 64 + i * 16 + lhi * 4 + rr;
        int s = (int)(r & 2047), b = (int)(r >> 11);
        unsigned short* dst = qf + (((long)(b * HH + h)) * SS + s) * 192;
        if (m192 < 128) {
#pragma unroll
          for (int j = 0; j < 4; ++j)
            dst[m192 + j * 16 + l15] = f2bf((acc[i][j][rr] + bv[j]) * scq);
        } else {
#pragma unroll
          for (int j = 0; j < 2; ++j) {
            int ifq = j * 16 + l15;
            float2 cs = rtab[s * 32 + ifq];
            float v1 = acc[i][j][rr] + bv[j];
            float v2 = acc[i][j + 2][rr] + bv[j + 2];
            dst[128 + ifq] = f2bf((v1 * cs.x - v2 * cs.y) * scq);
            dst[160 + ifq] = f2bf((v2 * cs.x + v1 * cs.y) * scq);
          }
        }
      }
    }
  } else if (blk < 1792) {
    // ---- kv GEMM with tiled epilogue ----
    const int K = 512;
    int b2 = blk - 768;
    int tm = b2 / 32, tn = b2 % 32;
    long row0 = (long)tm * 128, col0 = (long)tn * 128;
    f32x4 acc[4][4] = {};
    gemm_core64(kvn, wkvut, K, row0, col0, tid, lA, lB, acc);

    int base = (int)col0 + wc * 64;
    int h = base >> 8;
    bool isv = (base & 255) >= 128;   // block-uniform (tn parity)
    float bv[4];
#pragma unroll
    for (int j = 0; j < 4; ++j) bv[j] = bkvu[base + j * 16 + l15];
    int b = (int)(row0 >> 11);
    long bh = (long)b * HH + h;
    int lrb = wr * 64;
    __syncthreads();
    if (isv) {
#pragma unroll
      for (int i = 0; i < 4; ++i) {
        int lr = lrb + i * 16 + lhi * 4;
#pragma unroll
        for (int j = 0; j < 4; ++j) {
          int lc = wc * 64 + j * 16 + l15;
          ushort4 pk = { f2bf(acc[i][j][0] + bv[j]), f2bf(acc[i][j][1] + bv[j]),
                         f2bf(acc[i][j][2] + bv[j]), f2bf(acc[i][j][3] + bv[j]) };
          *(ushort4*)&smem[((lr >> 5) << 12) + lc * 32 + (lr & 31)] = pk;
        }
      }
      __syncthreads();
      long dst0 = (bh * 64 + ((row0 & 2047) >> 5)) * 4096;
#pragma unroll
      for (int p = 0; p < 8; ++p) {
        int e = p * 256 + tid;
        *(uint4*)&vt3[dst0 + e * 8] = *(uint4*)&smem[e * 8];
      }
    } else {
#pragma unroll
      for (int i = 0; i < 4; ++i) {
        int lr0 = lrb + i * 16 + lhi * 4;
#pragma unroll
        for (int j = 0; j < 4; ++j) {
          int c = (base & 255) + j * 16 + l15;   // 0..127
          int tbase = ((lr0 >> 4) << 11) + ((c >> 5) << 9) + (((c >> 3) & 3) << 7) + (c & 7);
#pragma unroll
          for (int rr = 0; rr < 4; ++rr)
            smem[tbase + ((lr0 + rr) & 15) * 8] = f2bf(acc[i][j][rr] + bv[j]);
        }
      }
      __syncthreads();
      long kb3 = (bh * 128 + ((row0 & 2047) >> 4)) * 3072;
#pragma unroll
      for (int p = 0; p < 8; ++p) {
        int e = p * 256 + tid;
        int tile = e >> 6;
        int off = (e & 63) * 8;
        long dst = kb3 + ((long)(tile >> 2) * 6 + (tile & 3)) * 512 + off;
        *(uint4*)&kf3[dst] = *(uint4*)&smem[tile * 512 + off];
      }
    }
  } else {
    // ---- krope: 4 rows per block ----
    int t = blk - 1792;
    int bs = t * 4 + (tid >> 6);
    int s = bs & (SS - 1), b = bs >> 11;
    const unsigned short* src = sCb + (long)bs * 2176 + 2048;
    int i = lane & 31;
    float2 cs = rtab[s * 32 + i];
    float t1 = bf2f(src[i]), t2 = bf2f(src[32 + i]);
    float v = (lane < 32) ? (t1 * cs.x - t2 * cs.y) : (t2 * cs.x + t1 * cs.y);
    unsigned short bv = f2bf(v);
    int d = 128 + lane;
    long inner = (long)(d >> 5) * 512 + ((d >> 3) & 3) * 128 + (s & 15) * 8 + (d & 7);
#pragma unroll
    for (int h = 0; h < HH; ++h) {
      long kblk = ((long)(b * HH + h) * 128 + (s >> 4)) * 6;
      kf3[kblk * 512 + inner] = bv;
    }
  }
}

// ---------------- merged RMSNorm (q rows then kv rows): bf16 -> bf16 ----------------
__global__ __launch_bounds__(256) void k_rmsnorm2(const unsigned short* __restrict__ sC,
                                                  const float* __restrict__ qnw,
                                                  const float* __restrict__ kvnw,
                                                  unsigned short* __restrict__ qn,
                                                  unsigned short* __restrict__ kvn) {
  int blk = blockIdx.x;
  long row;
  const unsigned short* x;
  const float* w;
  unsigned short* y;
  int L;
  if (blk < NROWS) {
    row = blk; x = sC + row * 2176; w = qnw; y = qn + row * 1536; L = 1536;
  } else {
    row = blk - NROWS; x = sC + row * 2176 + 1536; w = kvnw; y = kvn + row * 512; L = 512;
  }
  float ss = 0.f;
  int n4 = L >> 2;
  for (int i = threadIdx.x; i < n4; i += 256) {
    ushort4 v = ((const ushort4*)x)[i];
    float a = bf2f(v.x), bb = bf2f(v.y), c = bf2f(v.z), d = bf2f(v.w);
    ss += a * a + bb * bb + c * c + d * d;
  }
  for (int off = 32; off > 0; off >>= 1) ss += __shfl_xor(ss, off);
  __shared__ float sb[4];
  if ((threadIdx.x & 63) == 0) sb[threadIdx.x >> 6] = ss;
  __syncthreads();
  float scale = rsqrtf((sb[0] + sb[1] + sb[2] + sb[3]) / (float)L + 1e-6f);
  for (int i = threadIdx.x; i < L; i += 256)
    y[i] = f2bf(bf2f(x[i]) * scale * w[i]);
}

// ---------------- flash attention: deep split-KV (round-18 config, bf16 partials) ----------------
__global__ __launch_bounds__(256, 4) void k_attn(const unsigned short* __restrict__ qf,
                                                 const unsigned short* __restrict__ kf3,
                                                 const unsigned short* __restrict__ vt3,
                                                 unsigned short* __restrict__ o,
                                                 unsigned short* __restrict__ pOb,
                                                 float* __restrict__ pml) {
  __shared__ unsigned short kbuf[64 * 192];     // 24KB, single buffer
  __shared__ unsigned short pbuf[4][16 * 72];   // per-wave P transpose buffer (stride 72)
  int tid = threadIdx.x;
  int wave = tid >> 6, lane = tid & 63;
  int l15 = lane & 15, lhi = lane >> 4;
  int idx = blockIdx.x;
  int rp = idx >> 5, bh = idx & 31;
  int qt, part, np;
  if (rp < 32)      { qt = 24 + (rp >> 2); part = rp & 3; np = 4; }
  else if (rp < 56) { int r = rp - 32; qt = 16 + r / 3; part = r % 3; np = 3; }
  else if (rp < 72) { int r = rp - 56; qt = 8 + (r >> 1); part = r & 1; np = 2; }
  else              { qt = 79 - rp; part = 0; np = 1; }
  int nt = qt + 1;
  int t0 = nt * part / np, t1 = nt * (part + 1) / np;
  bool dodiag = (part == np - 1);
  int item;
  if (np == 1) item = -1;
  else {
    int base = (qt < 16) ? (qt - 8) * 2 : (qt < 24) ? 16 + (qt - 16) * 3 : 40 + (qt - 24) * 4;
    item = bh * 72 + base + part;
  }
  int b = bh >> 4, h = bh & 15;
  int q0 = qt * 64;
  const char* kbase = (const char*)(kf3 + (long)bh * 128 * 3072);
  const unsigned short* vfrag0 = vt3 + (long)bh * 64 * 4096 + l15 * 32 + lhi * 8;
  const unsigned short* kread = kbuf + lane * 8;
  unsigned psel = 0x07060302u;   // v_perm selector: {s0.hi16, s1.hi16}

  // prologue: stage K tile t0
  {
    const char* src = kbase + (long)t0 * 24576 + tid * 16;
    char* dst = (char*)kbuf + tid * 16;
#pragma unroll
    for (int p = 0; p < 6; ++p) gload16(src + p * 4096, dst + p * 4096);
  }

  // Q fragments (B-operand) — loads overlap stage latency
  const unsigned short* Qb = qf + ((long)bh * SS + q0 + wave * 16 + l15) * 192 + lhi * 8;
  bf16x8 qfr[6];
#pragma unroll
  for (int ks = 0; ks < 6; ++ks) qfr[ks] = *(const bf16x8*)(Qb + ks * 32);

  float m = -3e38f, ls = 0.f;
  f32x4 acc[8] = {};
  int qin = wave * 16 + l15;

  for (int t = t0; t < t1; ++t) {
    asm volatile("s_waitcnt vmcnt(0)" ::: "memory");
    __builtin_amdgcn_s_barrier();
    __builtin_amdgcn_sched_barrier(0);

    // QK^T (swapped): sc[nf] rows k=nf*16+lhi*4+j, col q=l15; conflict-free LDS reads
    f32x4 sc[4] = {};
    __builtin_amdgcn_s_setprio(1);
#pragma unroll
    for (int ks = 0; ks < 6; ++ks) {
      bf16x8 kfr[4];
#pragma unroll
      for (int nf = 0; nf < 4; ++nf)
        kfr[nf] = *(const bf16x8*)&kread[(nf * 6 + ks) * 512];
#pragma unroll
      for (int nf = 0; nf < 4; ++nf)
        sc[nf] = mfma16(kfr[nf], qfr[ks], sc[nf]);
    }
    __builtin_amdgcn_s_setprio(0);
    __builtin_amdgcn_sched_barrier(0);
    __builtin_amdgcn_s_barrier();          // all waves done reading kbuf
    __builtin_amdgcn_sched_barrier(0);

    // V batch 0 issue (softmax covers latency)
    const unsigned short* vtb = vfrag0 + (long)t * 8192;
    bf16x8 v0[8];
#pragma unroll
    for (int nf = 0; nf < 8; ++nf) v0[nf] = *(const bf16x8*)(vtb + nf * 512);
    __builtin_amdgcn_sched_barrier(0);

    // stage K tile t+1 (WAR barrier above; hides under softmax+PV)
    if (t + 1 < t1) {
      const char* src = kbase + (long)(t + 1) * 24576 + tid * 16;
      char* dst = (char*)kbuf + tid * 16;
#pragma unroll
      for (int p = 0; p < 6; ++p) gload16(src + p * 4096, dst + p * 4096);
    }

    // online softmax, lane-local over k
    bool diag = dodiag && (t == t1 - 1);
    float mnf[4];
#pragma unroll
    for (int nf = 0; nf < 4; ++nf) {
      if (diag) {
#pragma unroll
        for (int jj = 0; jj < 4; ++jj) {
          int kin = nf * 16 + lhi * 4 + jj;
          if (kin > qin) sc[nf][jj] = -3e38f;
        }
      }
      mnf[nf] = fmaxf(fmaxf(sc[nf][0], sc[nf][1]), fmaxf(sc[nf][2], sc[nf][3]));
    }
    float mx = fmaxf(fmaxf(mnf[0], mnf[1]), fmaxf(mnf[2], mnf[3]));
    mx = fmaxf(mx, __shfl_xor(mx, 16));
    mx = fmaxf(mx, __shfl_xor(mx, 32));
    if (!__all(mx <= m + 8.f)) {      // defer-rescale (exp2 domain, THR=8)
      float mn = fmaxf(m, mx);
      float alpha = exp2f(m - mn);
      m = mn;
      ls *= alpha;
#pragma unroll
      for (int nf = 0; nf < 8; ++nf)
#pragma unroll
        for (int jj = 0; jj < 4; ++jj) acc[nf][jj] *= alpha;
    }
    float pnf[4];
#pragma unroll
    for (int nf = 0; nf < 4; ++nf) {
      float e0 = exp2f(sc[nf][0] - m), e1 = exp2f(sc[nf][1] - m);
      float e2 = exp2f(sc[nf][2] - m), e3 = exp2f(sc[nf][3] - m);
      pnf[nf] = (e0 + e1) + (e2 + e3);
      unsigned lo, hi;   // pack 2 truncated bf16 per v_perm (P in [0,256): trunc err <0.4%)
      asm("v_perm_b32 %0, %1, %2, %3" : "=v"(lo) : "v"(e1), "v"(e0), "s"(psel));
      asm("v_perm_b32 %0, %1, %2, %3" : "=v"(hi) : "v"(e3), "v"(e2), "s"(psel));
      uint2 pk = { lo, hi };
      *(uint2*)&pbuf[wave][l15 * 72 + nf * 16 + lhi * 4] = pk;
    }
    float ps = (pnf[0] + pnf[1]) + (pnf[2] + pnf[3]);
    ps += __shfl_xor(ps, 16);
    ps += __shfl_xor(ps, 32);
    ls += ps;

    // PV kk=0 with v0
    {
      bf16x8 pf = *(const bf16x8*)&pbuf[wave][l15 * 72 + lhi * 8];
      __builtin_amdgcn_s_setprio(1);
#pragma unroll
      for (int nf = 0; nf < 8; ++nf) acc[nf] = mfma16(v0[nf], pf, acc[nf]);
      __builtin_amdgcn_s_setprio(0);
    }
    // V batch 1 (reuses v0's registers), then PV kk=1
    bf16x8 v1[8];
#pragma unroll
    for (int nf = 0; nf < 8; ++nf) v1[nf] = *(const bf16x8*)(vtb + 4096 + nf * 512);
    {
      bf16x8 pf = *(const bf16x8*)&pbuf[wave][l15 * 72 + 32 + lhi * 8];
      __builtin_amdgcn_s_setprio(1);
#pragma unroll
      for (int nf = 0; nf < 8; ++nf) acc[nf] = mfma16(v1[nf], pf, acc[nf]);
      __builtin_amdgcn_s_setprio(0);
    }
  }

  int qloc = wave * 16 + l15;
  if (item < 0) {
    // single: normalize + write o (row q=l15, d = nf*16+lhi*4+j)
    float invl = 1.f / ls;
    long orow = (long)b * SS + q0 + qloc;
#pragma unroll
    for (int nf = 0; nf < 8; ++nf) {
      ushort4 ov = { f2bf(acc[nf][0] * invl), f2bf(acc[nf][1] * invl),
                     f2bf(acc[nf][2] * invl), f2bf(acc[nf][3] * invl) };
      *(ushort4*)&o[orow * 2048 + h * 128 + nf * 16 + lhi * 4] = ov;
    }
  } else {
    // split: write unnormalized partials (bf16 — halves the partial traffic)
    unsigned short* po = pOb + (long)item * 8192 + qloc * 128;
#pragma unroll
    for (int nf = 0; nf < 8; ++nf) {
      ushort4 pv = { f2bf(acc[nf][0]), f2bf(acc[nf][1]),
                     f2bf(acc[nf][2]), f2bf(acc[nf][3]) };
      *(ushort4*)&po[nf * 16 + lhi * 4] = pv;
    }
    if (lhi == 0) {
      pml[(long)item * 128 + qloc * 2] = m;
      pml[(long)item * 128 + qloc * 2 + 1] = ls;
    }
  }
}

// ---------------- merge split-KV partials (2-4 parts, bf16) -> o ----------------
__global__ __launch_bounds__(256) void k_merge(const unsigned short* __restrict__ pOb,
                                               const float* __restrict__ pml,
                                               unsigned short* __restrict__ o) {
  int g = blockIdx.x;              // bh*24 + (qt-8)
  int bh = g / 24, qt = (g % 24) + 8;
  int b = bh >> 4, h = bh & 15;
  int q0 = qt * 64;
  int np = qt < 16 ? 2 : (qt < 24 ? 3 : 4);
  int base = (qt < 16) ? (qt - 8) * 2 : (qt < 24) ? 16 + (qt - 16) * 3 : 40 + (qt - 24) * 4;
  long i0 = (long)bh * 72 + base;
  __shared__ float wts[4][64];
  int tid = threadIdx.x;
  if (tid < 64) {
    float mp0 = -3e38f, mp1 = -3e38f, mp2 = -3e38f, mp3 = -3e38f;
    float lp0 = 0.f, lp1 = 0.f, lp2 = 0.f, lp3 = 0.f;
    mp0 = pml[(i0 + 0) * 128 + tid * 2]; lp0 = pml[(i0 + 0) * 128 + tid * 2 + 1];
    mp1 = pml[(i0 + 1) * 128 + tid * 2]; lp1 = pml[(i0 + 1) * 128 + tid * 2 + 1];
    if (np > 2) { mp2 = pml[(i0 + 2) * 128 + tid * 2]; lp2 = pml[(i0 + 2) * 128 + tid * 2 + 1]; }
    if (np > 3) { mp3 = pml[(i0 + 3) * 128 + tid * 2]; lp3 = pml[(i0 + 3) * 128 + tid * 2 + 1]; }
    float mm = fmaxf(fmaxf(mp0, mp1), fmaxf(mp2, mp3));
    float w0 = exp2f(mp0 - mm), w1 = exp2f(mp1 - mm);
    float w2 = (np > 2) ? exp2f(mp2 - mm) : 0.f;
    float w3 = (np > 3) ? exp2f(mp3 - mm) : 0.f;
    float inv = 1.f / (lp0 * w0 + lp1 * w1 + lp2 * w2 + lp3 * w3);
    wts[0][tid] = w0 * inv; wts[1][tid] = w1 * inv;
    wts[2][tid] = w2 * inv; wts[3][tid] = w3 * inv;
  }
  __syncthreads();
#pragma unroll
  for (int pp = 0; pp < 4; ++pp) {
    int e = pp * 256 + tid;          // uint4 units of 8 bf16: 1024 total
    int q = e >> 4, d8 = (e & 15) * 8;
    float s[8] = {};
#pragma unroll
    for (int p = 0; p < 4; ++p) {
      if (p < np) {
        uint4 v = *(const uint4*)&pOb[(i0 + p) * 8192 + q * 128 + d8];
        float w = wts[p][q];
        s[0] += bf2f((unsigned short)(v.x & 0xffff)) * w;
        s[1] += bf2f((unsigned short)(v.x >> 16)) * w;
        s[2] += bf2f((unsigned short)(v.y & 0xffff)) * w;
        s[3] += bf2f((unsigned short)(v.y >> 16)) * w;
        s[4] += bf2f((unsigned short)(v.z & 0xffff)) * w;
        s[5] += bf2f((unsigned short)(v.z >> 16)) * w;
        s[6] += bf2f((unsigned short)(v.w & 0xffff)) * w;
        s[7] += bf2f((unsigned short)(v.w >> 16)) * w;
      }
    }
    long ob_ = ((long)b * SS + q0 + q) * 2048 + h * 128 + d8;
    ushort4 o0 = { f2bf(s[0]), f2bf(s[1]), f2bf(s[2]), f2bf(s[3]) };
    ushort4 o1 = { f2bf(s[4]), f2bf(s[5]), f2bf(s[6]), f2bf(s[7]) };
    *(ushort4*)&o[ob_] = o0;
    *(ushort4*)&o[ob_ + 4] = o1;
  }
}

extern "C" void kernel_launch(void* const* d_in, const int* in_sizes, int n_in,
                              void* d_out, int out_size, void* d_ws, size_t ws_size,
                              hipStream_t stream) {
  const float* x    = (const float*)d_in[0];
  const float* wqd  = (const float*)d_in[1];
  const float* bqd  = (const float*)d_in[2];
  const float* qnw  = (const float*)d_in[3];
  const float* wqu  = (const float*)d_in[4];
  const float* bqu  = (const float*)d_in[5];
  const float* wkvd = (const float*)d_in[6];
  const float* bkvd = (const float*)d_in[7];
  const float* kvnw = (const float*)d_in[8];
  const float* wkvu = (const float*)d_in[9];
  const float* bkvu = (const float*)d_in[10];
  const float* wout = (const float*)d_in[11];
  const float* bout = (const float*)d_in[12];
  float* out = (float*)d_out;

  char* ws = (char*)d_ws;
  size_t off = 0;
  auto alloc = [&](size_t sz) {
    char* p = ws + off;
    off += (sz + 255) & ~(size_t)255;
    return p;
  };
  unsigned short* xb    = (unsigned short*)alloc((size_t)NROWS * 2048 * 2);
  unsigned short* wqkt  = (unsigned short*)alloc((size_t)2176 * 2048 * 2);  // [wqd;wkvd]^T
  unsigned short* wqut  = (unsigned short*)alloc((size_t)3072 * 1536 * 2);
  unsigned short* wkvut = (unsigned short*)alloc((size_t)4096 * 512 * 2);
  unsigned short* woutt = (unsigned short*)alloc((size_t)2048 * 2048 * 2);
  unsigned short* qn    = (unsigned short*)alloc((size_t)NROWS * 1536 * 2);
  unsigned short* kvn   = (unsigned short*)alloc((size_t)NROWS * 512 * 2);
  unsigned short* qfb   = (unsigned short*)alloc((size_t)32 * SS * 192 * 2);
  unsigned short* kfb   = (unsigned short*)alloc((size_t)32 * SS * 192 * 2);   // kf3 tiled
  unsigned short* vtb   = (unsigned short*)alloc((size_t)32 * 128 * SS * 2);   // vt3 tiled
  unsigned short* ob    = (unsigned short*)alloc((size_t)NROWS * 2048 * 2);
  float*  mbias = (float*)alloc((size_t)2176 * 4);
  float2* rtab  = (float2*)alloc((size_t)SS * 32 * 8);
  unsigned short* pOb = (unsigned short*)alloc((size_t)2304 * 8192 * 2);   // 37.7 MB bf16 partials
  float*  pml   = (float*)alloc((size_t)2304 * 128 * 4);    // partial m/ls
  unsigned short* sCb = (unsigned short*)alloc((size_t)NROWS * 2176 * 2);  // merged qd|kvd (bf16)

  // fused preprocessing: convert + 5 transposes + bias merge + rope table
  k_prep<<<17417, 256, 0, stream>>>(x, xb, wqd, wqu, wkvd, wkvu, wout,
                                    wqkt, wqut, wkvut, woutt, bqd, bkvd, mbias, rtab);

  // down-projections (merged, bf16 out): sCb = x @ [wqd|wkvd] + bias
  k_gemm_c16<<<32 * 17, 256, 0, stream>>>(xb, wqkt, mbias, sCb, NROWS, 2176, 2048);

  // both rmsnorms in one launch
  k_rmsnorm2<<<2 * NROWS, 256, 0, stream>>>(sCb, qnw, kvnw, qn, kvn);

  // up-projections + krope in one launch
  k_up<<<2816, 256, 0, stream>>>(qn, wqut, bqu, kvn, wkvut, bkvu, sCb, rtab,
                                 qfb, kfb, vtb);

  // attention: deep split-KV (2560 blocks, max 9 iters) + merge
  k_attn<<<2560, 256, 0, stream>>>(qfb, kfb, vtb, ob, pOb, pml);
  k_merge<<<768, 256, 0, stream>>>(pOb, pml, ob);

  // output projection
  k_gemm<<<32 * 16, 256, 0, stream>>>(ob, woutt, bout, out, NROWS, 2048, 2048);
}

// Round 20
// 343.303 us; speedup vs baseline: 1.7746x; 1.0077x over previous
//
#include <hip/hip_runtime.h>
#include <hip/hip_bf16.h>
#include <math.h>

#define HH 16
#define SS 2048
#define BBATCH 2
#define NROWS 4096   // B*S

typedef __attribute__((ext_vector_type(8))) __bf16 bf16x8;
typedef __attribute__((ext_vector_type(4))) float f32x4;
typedef const __attribute__((address_space(1))) unsigned int* gas1_t;
typedef __attribute__((address_space(3))) unsigned int* las3_t;

__device__ __forceinline__ unsigned short f2bf(float f) {
  unsigned u = __builtin_bit_cast(unsigned, f);
  u += 0x7fffu + ((u >> 16) & 1u);
  return (unsigned short)(u >> 16);
}
__device__ __forceinline__ float bf2f(unsigned short u) {
  return __builtin_bit_cast(float, (unsigned)u << 16);
}

__device__ __forceinline__ void gload16(const void* g, void* l) {
  __builtin_amdgcn_global_load_lds((gas1_t)g, (las3_t)l, 16, 0, 0);
}
__device__ __forceinline__ f32x4 mfma16(bf16x8 a, bf16x8 b, f32x4 c) {
  return __builtin_amdgcn_mfma_f32_16x16x32_bf16(a, b, c, 0, 0, 0);
}

// ---------------- shared BK=64 GEMM core (128x128 tile, 4 waves) ----------------
// Staging: global source pre-swizzled per granule (cg ^= row&7), LDS dest linear
// (swizzle both sides or neither with global_load_lds). Reads apply the same
// XOR -> 8-way max bank aliasing; barrier/drain count per 64 K-elements halved.
__device__ __forceinline__ void gemm_core64(const unsigned short* __restrict__ A,
                                            const unsigned short* __restrict__ Bt,
                                            int K, long row0, long col0, int tid,
                                            unsigned short* lA, unsigned short* lB,
                                            f32x4 (*acc)[4]) {
  int wave = tid >> 6, lane = tid & 63;
  int l15 = lane & 15, lhi = lane >> 4;
  int wr = wave >> 1, wc = wave & 1;
  int trow = tid >> 3, tcg = tid & 7;
  const unsigned short* gA = A + (row0 + trow) * K + ((tcg ^ (trow & 7)) * 8);
  const unsigned short* gB = Bt + (col0 + trow) * K + ((tcg ^ (trow & 7)) * 8);
  unsigned short* lA0 = &lA[tid * 8];
  unsigned short* lB0 = &lB[tid * 8];
  for (int k0 = 0; k0 < K; k0 += 64) {
    __syncthreads();
#pragma unroll
    for (int p = 0; p < 4; ++p) {
      gload16(gA + (long)p * 32 * K + k0, lA0 + p * 2048);
      gload16(gB + (long)p * 32 * K + k0, lB0 + p * 2048);
    }
    asm volatile("s_waitcnt vmcnt(0)" ::: "memory");
    __syncthreads();
#pragma unroll
    for (int kk = 0; kk < 2; ++kk) {
      bf16x8 af[4], bfr[4];
#pragma unroll
      for (int i = 0; i < 4; ++i) {
        int rA = wr * 64 + i * 16 + l15;
        int rB = wc * 64 + i * 16 + l15;
        af[i]  = *(const bf16x8*)&lA[rA * 64 + (((kk * 4 + lhi) ^ (rA & 7)) * 8)];
        bfr[i] = *(const bf16x8*)&lB[rB * 64 + (((kk * 4 + lhi) ^ (rB & 7)) * 8)];
      }
#pragma unroll
      for (int i = 0; i < 4; ++i)
#pragma unroll
        for (int j = 0; j < 4; ++j)
          acc[i][j] = mfma16(af[i], bfr[j], acc[i][j]);
    }
  }
}

// ---------------- transpose body: W (K,N) f32 -> Wt (Npad,K) bf16 ----------------
__device__ __forceinline__ void transpose_body(const float* __restrict__ W,
                                               unsigned short* __restrict__ Wt,
                                               int K, int N, int Npad,
                                               int bx, int by, float (*tile)[33], int tid) {
  int n0 = bx * 32, k0 = by * 32;
  int tx = tid & 31, ty = tid >> 5;
  for (int i = ty; i < 32; i += 8) {
    int k = k0 + i, n = n0 + tx;
    tile[i][tx] = (k < K && n < N) ? W[(long)k * N + n] : 0.f;
  }
  __syncthreads();
  for (int i = ty; i < 32; i += 8) {
    int n = n0 + i, k = k0 + tx;
    if (n < Npad && k < K) Wt[(long)n * K + k] = f2bf(tile[tx][i]);
  }
}

// ---------------- fused preprocessing: convert + 5 transposes + bias + rope table ----------------
__global__ __launch_bounds__(256) void k_prep(const float* __restrict__ x,
                                              unsigned short* __restrict__ xb,
                                              const float* __restrict__ wqd,
                                              const float* __restrict__ wqu,
                                              const float* __restrict__ wkvd,
                                              const float* __restrict__ wkvu,
                                              const float* __restrict__ wout,
                                              unsigned short* __restrict__ wqkt,
                                              unsigned short* __restrict__ wqut,
                                              unsigned short* __restrict__ wkvut,
                                              unsigned short* __restrict__ woutt,
                                              const float* __restrict__ bqd,
                                              const float* __restrict__ bkvd,
                                              float* __restrict__ mbias,
                                              float2* __restrict__ rtab) {
  __shared__ float tile[32][33];
  int blk = blockIdx.x;
  int tid = threadIdx.x;
  if (blk < 2048) {
    long n4 = (long)NROWS * 2048 / 4;
    for (long i = (long)blk * 256 + tid; i < n4; i += 2048 * 256) {
      float4 v = ((const float4*)x)[i];
      ushort4 o = { f2bf(v.x), f2bf(v.y), f2bf(v.z), f2bf(v.w) };
      ((ushort4*)xb)[i] = o;
    }
  } else if (blk < 5120) {
    int t = blk - 2048;
    transpose_body(wqd, wqkt, 2048, 1536, 1536, t % 48, t / 48, tile, tid);
  } else if (blk < 9728) {
    int t = blk - 5120;
    transpose_body(wqu, wqut, 1536, 3072, 3072, t % 96, t / 96, tile, tid);
  } else if (blk < 11008) {
    int t = blk - 9728;
    transpose_body(wkvd, wqkt + (size_t)1536 * 2048, 2048, 576, 640, t % 20, t / 20, tile, tid);
  } else if (blk < 13056) {
    int t = blk - 11008;
    transpose_body(wkvu, wkvut, 512, 4096, 4096, t % 128, t / 128, tile, tid);
  } else if (blk < 17152) {
    int t = blk - 13056;
    transpose_body(wout, woutt, 2048, 2048, 2048, t % 64, t / 64, tile, tid);
  } else if (blk < 17161) {
    int i = (blk - 17152) * 256 + tid;
    if (i < 2176) mbias[i] = i < 1536 ? bqd[i] : (i < 2112 ? bkvd[i - 1536] : 0.f);
  } else {
    int t = blk - 17161;                    // 256 blocks, 8 s each
    int s = t * 8 + (tid >> 5);
    int i = tid & 31;
    float inv = powf(10000.f, -(float)i / 32.f);
    float ang = (float)s * inv;
    float sn, cs;
    sincosf(ang, &sn, &cs);
    rtab[s * 32 + i] = make_float2(cs, sn);
  }
}

// ---------------- GEMM: C(M,N) f32 = A(M,K)bf16 * Bt(Npad,K)bf16 + bias ----------------
// XCD-bijective block swizzle (gridDim.x % 8 == 0): each XCD gets a contiguous
// tile range -> A-panel L2 reuse within the XCD.
__global__ __launch_bounds__(256) void k_gemm(const unsigned short* __restrict__ A,
                                              const unsigned short* __restrict__ Bt,
                                              const float* __restrict__ bias,
                                              float* __restrict__ C,
                                              int M, int N, int K) {
  __shared__ unsigned short lA[128 * 64];
  __shared__ unsigned short lB[128 * 64];
  int tid = threadIdx.x;
  int wave = tid >> 6, lane = tid & 63;
  int l15 = lane & 15, lhi = lane >> 4;
  int bswz = (blockIdx.x & 7) * (gridDim.x >> 3) + (blockIdx.x >> 3);
  int ntn = (N + 127) >> 7;
  int tm = bswz / ntn, tn = bswz % ntn;
  long row0 = (long)tm * 128, col0 = (long)tn * 128;
  int wr = wave >> 1, wc = wave & 1;

  f32x4 acc[4][4] = {};
  gemm_core64(A, Bt, K, row0, col0, tid, lA, lB, acc);

#pragma unroll
  for (int i = 0; i < 4; ++i)
#pragma unroll
    for (int j = 0; j < 4; ++j) {
      long r = row0 + wr * 64 + i * 16 + lhi * 4;
      long c = col0 + wc * 64 + j * 16 + l15;
      if (c < N) {
        float bv = bias[c];
#pragma unroll
        for (int rr = 0; rr < 4; ++rr)
          C[(r + rr) * N + c] = acc[i][j][rr] + bv;
      }
    }
}

// ---------------- GEMM with bf16 output (down-proj -> sC bf16), XCD swizzle ----------------
__global__ __launch_bounds__(256) void k_gemm_c16(const unsigned short* __restrict__ A,
                                                  const unsigned short* __restrict__ Bt,
                                                  const float* __restrict__ bias,
                                                  unsigned short* __restrict__ C,
                                                  int M, int N, int K) {
  __shared__ unsigned short lA[128 * 64];
  __shared__ unsigned short lB[128 * 64];
  int tid = threadIdx.x;
  int wave = tid >> 6, lane = tid & 63;
  int l15 = lane & 15, lhi = lane >> 4;
  int bswz = (blockIdx.x & 7) * (gridDim.x >> 3) + (blockIdx.x >> 3);
  int ntn = (N + 127) >> 7;
  int tm = bswz / ntn, tn = bswz % ntn;
  long row0 = (long)tm * 128, col0 = (long)tn * 128;
  int wr = wave >> 1, wc = wave & 1;

  f32x4 acc[4][4] = {};
  gemm_core64(A, Bt, K, row0, col0, tid, lA, lB, acc);

#pragma unroll
  for (int i = 0; i < 4; ++i)
#pragma unroll
    for (int j = 0; j < 4; ++j) {
      long r = row0 + wr * 64 + i * 16 + lhi * 4;
      long c = col0 + wc * 64 + j * 16 + l15;
      if (c < N) {
        float bv = bias[c];
#pragma unroll
        for (int rr = 0; rr < 4; ++rr)
          C[(r + rr) * N + c] = f2bf(acc[i][j][rr] + bv);
      }
    }
}

// ---------------- merged up-projections + krope in ONE launch ----------------
// blocks [0,768): qf GEMM; [768,1792): kv GEMM; [1792,2816): krope.
// Each GEMM section gets its own XCD-bijective swizzle (section sizes % 8 == 0
// and section starts % 8 == 0, so blockIdx%8 alignment holds per section).
__global__ __launch_bounds__(256) void k_up(const unsigned short* __restrict__ qn,
                                            const unsigned short* __restrict__ wqut,
                                            const float* __restrict__ bqu,
                                            const unsigned short* __restrict__ kvn,
                                            const unsigned short* __restrict__ wkvut,
                                            const float* __restrict__ bkvu,
                                            const unsigned short* __restrict__ sCb,
                                            const float2* __restrict__ rtab,
                                            unsigned short* __restrict__ qf,
                                            unsigned short* __restrict__ kf3,
                                            unsigned short* __restrict__ vt3) {
  __shared__ unsigned short smem[16384];   // 32KB: lA/lB in loop, stage in epilogue
  unsigned short* lA = smem;
  unsigned short* lB = smem + 8192;
  int blk = blockIdx.x;
  int tid = threadIdx.x;
  int wave = tid >> 6, lane = tid & 63;
  int l15 = lane & 15, lhi = lane >> 4;
  int wr = wave >> 1, wc = wave & 1;

  if (blk < 768) {
    // ---- qf GEMM ----
    const int K = 1536;
    int bswz = (blk & 7) * 96 + (blk >> 3);
    int tm = bswz / 24, tn = bswz % 24;
    long row0 = (long)tm * 128, col0 = (long)tn * 128;
    f32x4 acc[4][4] = {};
    gemm_core64(qn, wqut, K, row0, col0, tid, lA, lB, acc);

    const float scq = 0.07216878364870322f * 1.4426950408889634f;  // 192^-0.5 * log2(e)
    int base = (int)col0 + wc * 64;
    int h = base / 192;
    int m192 = base - h * 192;   // 0, 64, or 128 (wave-uniform)
    float bv[4];
#pragma unroll
    for (int j = 0; j < 4; ++j) bv[j] = bqu[base + j * 16 + l15];
#pragma unroll
    for (int i = 0; i < 4; ++i) {
#pragma unroll
      for (int rr = 0; rr < 4; ++rr) {
        long r = row0 + wr * 64 + i * 16 + lhi * 4 + rr;
        int s = (int)(r & 2047), b = (int)(r >> 11);
        unsigned short* dst = qf + (((long)(b * HH + h)) * SS + s) * 192;
        if (m192 < 128) {
#pragma unroll
          for (int j = 0; j < 4; ++j)
            dst[m192 + j * 16 + l15] = f2bf((acc[i][j][rr] + bv[j]) * scq);
        } else {
#pragma unroll
          for (int j = 0; j < 2; ++j) {
            int ifq = j * 16 + l15;
            float2 cs = rtab[s * 32 + ifq];
            float v1 = acc[i][j][rr] + bv[j];
            float v2 = acc[i][j + 2][rr] + bv[j + 2];
            dst[128 + ifq] = f2bf((v1 * cs.x - v2 * cs.y) * scq);
            dst[160 + ifq] = f2bf((v2 * cs.x + v1 * cs.y) * scq);
          }
        }
      }
    }
  } else if (blk < 1792) {
    // ---- kv GEMM with tiled epilogue ----
    const int K = 512;
    int b2 = blk - 768;
    int bswz = (b2 & 7) * 128 + (b2 >> 3);
    int tm = bswz / 32, tn = bswz % 32;
    long row0 = (long)tm * 128, col0 = (long)tn * 128;
    f32x4 acc[4][4] = {};
    gemm_core64(kvn, wkvut, K, row0, col0, tid, lA, lB, acc);

    int base = (int)col0 + wc * 64;
    int h = base >> 8;
    bool isv = (base & 255) >= 128;   // block-uniform (tn parity)
    float bv[4];
#pragma unroll
    for (int j = 0; j < 4; ++j) bv[j] = bkvu[base + j * 16 + l15];
    int b = (int)(row0 >> 11);
    long bh = (long)b * HH + h;
    int lrb = wr * 64;
    __syncthreads();
    if (isv) {
#pragma unroll
      for (int i = 0; i < 4; ++i) {
        int lr = lrb + i * 16 + lhi * 4;
#pragma unroll
        for (int j = 0; j < 4; ++j) {
          int lc = wc * 64 + j * 16 + l15;
          ushort4 pk = { f2bf(acc[i][j][0] + bv[j]), f2bf(acc[i][j][1] + bv[j]),
                         f2bf(acc[i][j][2] + bv[j]), f2bf(acc[i][j][3] + bv[j]) };
          *(ushort4*)&smem[((lr >> 5) << 12) + lc * 32 + (lr & 31)] = pk;
        }
      }
      __syncthreads();
      long dst0 = (bh * 64 + ((row0 & 2047) >> 5)) * 4096;
#pragma unroll
      for (int p = 0; p < 8; ++p) {
        int e = p * 256 + tid;
        *(uint4*)&vt3[dst0 + e * 8] = *(uint4*)&smem[e * 8];
      }
    } else {
#pragma unroll
      for (int i = 0; i < 4; ++i) {
        int lr0 = lrb + i * 16 + lhi * 4;
#pragma unroll
        for (int j = 0; j < 4; ++j) {
          int c = (base & 255) + j * 16 + l15;   // 0..127
          int tbase = ((lr0 >> 4) << 11) + ((c >> 5) << 9) + (((c >> 3) & 3) << 7) + (c & 7);
#pragma unroll
          for (int rr = 0; rr < 4; ++rr)
            smem[tbase + ((lr0 + rr) & 15) * 8] = f2bf(acc[i][j][rr] + bv[j]);
        }
      }
      __syncthreads();
      long kb3 = (bh * 128 + ((row0 & 2047) >> 4)) * 3072;
#pragma unroll
      for (int p = 0; p < 8; ++p) {
        int e = p * 256 + tid;
        int tile = e >> 6;
        int off = (e & 63) * 8;
        long dst = kb3 + ((long)(tile >> 2) * 6 + (tile & 3)) * 512 + off;
        *(uint4*)&kf3[dst] = *(uint4*)&smem[tile * 512 + off];
      }
    }
  } else {
    // ---- krope: 4 rows per block ----
    int t = blk - 1792;
    int bs = t * 4 + (tid >> 6);
    int s = bs & (SS - 1), b = bs >> 11;
    const unsigned short* src = sCb + (long)bs * 2176 + 2048;
    int i = lane & 31;
    float2 cs = rtab[s * 32 + i];
    float t1 = bf2f(src[i]), t2 = bf2f(src[32 + i]);
    float v = (lane < 32) ? (t1 * cs.x - t2 * cs.y) : (t2 * cs.x + t1 * cs.y);
    unsigned short bv = f2bf(v);
    int d = 128 + lane;
    long inner = (long)(d >> 5) * 512 + ((d >> 3) & 3) * 128 + (s & 15) * 8 + (d & 7);
#pragma unroll
    for (int h = 0; h < HH; ++h) {
      long kblk = ((long)(b * HH + h) * 128 + (s >> 4)) * 6;
      kf3[kblk * 512 + inner] = bv;
    }
  }
}

// ---------------- merged RMSNorm (q rows then kv rows): bf16 -> bf16 ----------------
__global__ __launch_bounds__(256) void k_rmsnorm2(const unsigned short* __restrict__ sC,
                                                  const float* __restrict__ qnw,
                                                  const float* __restrict__ kvnw,
                                                  unsigned short* __restrict__ qn,
                                                  unsigned short* __restrict__ kvn) {
  int blk = blockIdx.x;
  long row;
  const unsigned short* x;
  const float* w;
  unsigned short* y;
  int L;
  if (blk < NROWS) {
    row = blk; x = sC + row * 2176; w = qnw; y = qn + row * 1536; L = 1536;
  } else {
    row = blk - NROWS; x = sC + row * 2176 + 1536; w = kvnw; y = kvn + row * 512; L = 512;
  }
  float ss = 0.f;
  int n4 = L >> 2;
  for (int i = threadIdx.x; i < n4; i += 256) {
    ushort4 v = ((const ushort4*)x)[i];
    float a = bf2f(v.x), bb = bf2f(v.y), c = bf2f(v.z), d = bf2f(v.w);
    ss += a * a + bb * bb + c * c + d * d;
  }
  for (int off = 32; off > 0; off >>= 1) ss += __shfl_xor(ss, off);
  __shared__ float sb[4];
  if ((threadIdx.x & 63) == 0) sb[threadIdx.x >> 6] = ss;
  __syncthreads();
  float scale = rsqrtf((sb[0] + sb[1] + sb[2] + sb[3]) / (float)L + 1e-6f);
  for (int i = threadIdx.x; i < L; i += 256)
    y[i] = f2bf(bf2f(x[i]) * scale * w[i]);
}

// ---------------- flash attention: deep split-KV (bf16 partials) ----------------
__global__ __launch_bounds__(256, 4) void k_attn(const unsigned short* __restrict__ qf,
                                                 const unsigned short* __restrict__ kf3,
                                                 const unsigned short* __restrict__ vt3,
                                                 unsigned short* __restrict__ o,
                                                 unsigned short* __restrict__ pOb,
                                                 float* __restrict__ pml) {
  __shared__ unsigned short kbuf[64 * 192];     // 24KB, single buffer
  __shared__ unsigned short pbuf[4][16 * 72];   // per-wave P transpose buffer (stride 72)
  int tid = threadIdx.x;
  int wave = tid >> 6, lane = tid & 63;
  int l15 = lane & 15, lhi = lane >> 4;
  int idx = blockIdx.x;
  int rp = idx >> 5, bh = idx & 31;
  int qt, part, np;
  if (rp < 32)      { qt = 24 + (rp >> 2); part = rp & 3; np = 4; }
  else if (rp < 56) { int r = rp - 32; qt = 16 + r / 3; part = r % 3; np = 3; }
  else if (rp < 72) { int r = rp - 56; qt = 8 + (r >> 1); part = r & 1; np = 2; }
  else              { qt = 79 - rp; part = 0; np = 1; }
  int nt = qt + 1;
  int t0 = nt * part / np, t1 = nt * (part + 1) / np;
  bool dodiag = (part == np - 1);
  int item;
  if (np == 1) item = -1;
  else {
    int base = (qt < 16) ? (qt - 8) * 2 : (qt < 24) ? 16 + (qt - 16) * 3 : 40 + (qt - 24) * 4;
    item = bh * 72 + base + part;
  }
  int b = bh >> 4, h = bh & 15;
  int q0 = qt * 64;
  const char* kbase = (const char*)(kf3 + (long)bh * 128 * 3072);
  const unsigned short* vfrag0 = vt3 + (long)bh * 64 * 4096 + l15 * 32 + lhi * 8;
  const unsigned short* kread = kbuf + lane * 8;
  unsigned psel = 0x07060302u;   // v_perm selector: {s0.hi16, s1.hi16}

  // prologue: stage K tile t0
  {
    const char* src = kbase + (long)t0 * 24576 + tid * 16;
    char* dst = (char*)kbuf + tid * 16;
#pragma unroll
    for (int p = 0; p < 6; ++p) gload16(src + p * 4096, dst + p * 4096);
  }

  // Q fragments (B-operand) — loads overlap stage latency
  const unsigned short* Qb = qf + ((long)bh * SS + q0 + wave * 16 + l15) * 192 + lhi * 8;
  bf16x8 qfr[6];
#pragma unroll
  for (int ks = 0; ks < 6; ++ks) qfr[ks] = *(const bf16x8*)(Qb + ks * 32);

  float m = -3e38f, ls = 0.f;
  f32x4 acc[8] = {};
  int qin = wave * 16 + l15;

  for (int t = t0; t < t1; ++t) {
    asm volatile("s_waitcnt vmcnt(0)" ::: "memory");
    __builtin_amdgcn_s_barrier();
    __builtin_amdgcn_sched_barrier(0);

    // QK^T (swapped): sc[nf] rows k=nf*16+lhi*4+j, col q=l15; conflict-free LDS reads
    f32x4 sc[4] = {};
    __builtin_amdgcn_s_setprio(1);
#pragma unroll
    for (int ks = 0; ks < 6; ++ks) {
      bf16x8 kfr[4];
#pragma unroll
      for (int nf = 0; nf < 4; ++nf)
        kfr[nf] = *(const bf16x8*)&kread[(nf * 6 + ks) * 512];
#pragma unroll
      for (int nf = 0; nf < 4; ++nf)
        sc[nf] = mfma16(kfr[nf], qfr[ks], sc[nf]);
    }
    __builtin_amdgcn_s_setprio(0);
    __builtin_amdgcn_sched_barrier(0);
    __builtin_amdgcn_s_barrier();          // all waves done reading kbuf
    __builtin_amdgcn_sched_barrier(0);

    // V batch 0 issue (softmax covers latency)
    const unsigned short* vtb = vfrag0 + (long)t * 8192;
    bf16x8 v0[8];
#pragma unroll
    for (int nf = 0; nf < 8; ++nf) v0[nf] = *(const bf16x8*)(vtb + nf * 512);
    __builtin_amdgcn_sched_barrier(0);

    // stage K tile t+1 (WAR barrier above; hides under softmax+PV)
    if (t + 1 < t1) {
      const char* src = kbase + (long)(t + 1) * 24576 + tid * 16;
      char* dst = (char*)kbuf + tid * 16;
#pragma unroll
      for (int p = 0; p < 6; ++p) gload16(src + p * 4096, dst + p * 4096);
    }

    // online softmax, lane-local over k
    bool diag = dodiag && (t == t1 - 1);
    float mnf[4];
#pragma unroll
    for (int nf = 0; nf < 4; ++nf) {
      if (diag) {
#pragma unroll
        for (int jj = 0; jj < 4; ++jj) {
          int kin = nf * 16 + lhi * 4 + jj;
          if (kin > qin) sc[nf][jj] = -3e38f;
        }
      }
      mnf[nf] = fmaxf(fmaxf(sc[nf][0], sc[nf][1]), fmaxf(sc[nf][2], sc[nf][3]));
    }
    float mx = fmaxf(fmaxf(mnf[0], mnf[1]), fmaxf(mnf[2], mnf[3]));
    mx = fmaxf(mx, __shfl_xor(mx, 16));
    mx = fmaxf(mx, __shfl_xor(mx, 32));
    if (!__all(mx <= m + 8.f)) {      // defer-rescale (exp2 domain, THR=8)
      float mn = fmaxf(m, mx);
      float alpha = exp2f(m - mn);
      m = mn;
      ls *= alpha;
#pragma unroll
      for (int nf = 0; nf < 8; ++nf)
#pragma unroll
        for (int jj = 0; jj < 4; ++jj) acc[nf][jj] *= alpha;
    }
    float pnf[4];
#pragma unroll
    for (int nf = 0; nf < 4; ++nf) {
      float e0 = exp2f(sc[nf][0] - m), e1 = exp2f(sc[nf][1] - m);
      float e2 = exp2f(sc[nf][2] - m), e3 = exp2f(sc[nf][3] - m);
      pnf[nf] = (e0 + e1) + (e2 + e3);
      unsigned lo, hi;   // pack 2 truncated bf16 per v_perm (P in [0,256): trunc err <0.4%)
      asm("v_perm_b32 %0, %1, %2, %3" : "=v"(lo) : "v"(e1), "v"(e0), "s"(psel));
      asm("v_perm_b32 %0, %1, %2, %3" : "=v"(hi) : "v"(e3), "v"(e2), "s"(psel));
      uint2 pk = { lo, hi };
      *(uint2*)&pbuf[wave][l15 * 72 + nf * 16 + lhi * 4] = pk;
    }
    float ps = (pnf[0] + pnf[1]) + (pnf[2] + pnf[3]);
    ps += __shfl_xor(ps, 16);
    ps += __shfl_xor(ps, 32);
    ls += ps;

    // PV kk=0 with v0
    {
      bf16x8 pf = *(const bf16x8*)&pbuf[wave][l15 * 72 + lhi * 8];
      __builtin_amdgcn_s_setprio(1);
#pragma unroll
      for (int nf = 0; nf < 8; ++nf) acc[nf] = mfma16(v0[nf], pf, acc[nf]);
      __builtin_amdgcn_s_setprio(0);
    }
    // V batch 1 (reuses v0's registers), then PV kk=1
    bf16x8 v1[8];
#pragma unroll
    for (int nf = 0; nf < 8; ++nf) v1[nf] = *(const bf16x8*)(vtb + 4096 + nf * 512);
    {
      bf16x8 pf = *(const bf16x8*)&pbuf[wave][l15 * 72 + 32 + lhi * 8];
      __builtin_amdgcn_s_setprio(1);
#pragma unroll
      for (int nf = 0; nf < 8; ++nf) acc[nf] = mfma16(v1[nf], pf, acc[nf]);
      __builtin_amdgcn_s_setprio(0);
    }
  }

  int qloc = wave * 16 + l15;
  if (item < 0) {
    // single: normalize + write o (row q=l15, d = nf*16+lhi*4+j)
    float invl = 1.f / ls;
    long orow = (long)b * SS + q0 + qloc;
#pragma unroll
    for (int nf = 0; nf < 8; ++nf) {
      ushort4 ov = { f2bf(acc[nf][0] * invl), f2bf(acc[nf][1] * invl),
                     f2bf(acc[nf][2] * invl), f2bf(acc[nf][3] * invl) };
      *(ushort4*)&o[orow * 2048 + h * 128 + nf * 16 + lhi * 4] = ov;
    }
  } else {
    // split: write unnormalized partials (bf16 — halves the partial traffic)
    unsigned short* po = pOb + (long)item * 8192 + qloc * 128;
#pragma unroll
    for (int nf = 0; nf < 8; ++nf) {
      ushort4 pv = { f2bf(acc[nf][0]), f2bf(acc[nf][1]),
                     f2bf(acc[nf][2]), f2bf(acc[nf][3]) };
      *(ushort4*)&po[nf * 16 + lhi * 4] = pv;
    }
    if (lhi == 0) {
      pml[(long)item * 128 + qloc * 2] = m;
      pml[(long)item * 128 + qloc * 2 + 1] = ls;
    }
  }
}

// ---------------- merge split-KV partials (2-4 parts, bf16) -> o ----------------
__global__ __launch_bounds__(256) void k_merge(const unsigned short* __restrict__ pOb,
                                               const float* __restrict__ pml,
                                               unsigned short* __restrict__ o) {
  int g = blockIdx.x;              // bh*24 + (qt-8)
  int bh = g / 24, qt = (g % 24) + 8;
  int b = bh >> 4, h = bh & 15;
  int q0 = qt * 64;
  int np = qt < 16 ? 2 : (qt < 24 ? 3 : 4);
  int base = (qt < 16) ? (qt - 8) * 2 : (qt < 24) ? 16 + (qt - 16) * 3 : 40 + (qt - 24) * 4;
  long i0 = (long)bh * 72 + base;
  __shared__ float wts[4][64];
  int tid = threadIdx.x;
  if (tid < 64) {
    float mp0 = -3e38f, mp1 = -3e38f, mp2 = -3e38f, mp3 = -3e38f;
    float lp0 = 0.f, lp1 = 0.f, lp2 = 0.f, lp3 = 0.f;
    mp0 = pml[(i0 + 0) * 128 + tid * 2]; lp0 = pml[(i0 + 0) * 128 + tid * 2 + 1];
    mp1 = pml[(i0 + 1) * 128 + tid * 2]; lp1 = pml[(i0 + 1) * 128 + tid * 2 + 1];
    if (np > 2) { mp2 = pml[(i0 + 2) * 128 + tid * 2]; lp2 = pml[(i0 + 2) * 128 + tid * 2 + 1]; }
    if (np > 3) { mp3 = pml[(i0 + 3) * 128 + tid * 2]; lp3 = pml[(i0 + 3) * 128 + tid * 2 + 1]; }
    float mm = fmaxf(fmaxf(mp0, mp1), fmaxf(mp2, mp3));
    float w0 = exp2f(mp0 - mm), w1 = exp2f(mp1 - mm);
    float w2 = (np > 2) ? exp2f(mp2 - mm) : 0.f;
    float w3 = (np > 3) ? exp2f(mp3 - mm) : 0.f;
    float inv = 1.f / (lp0 * w0 + lp1 * w1 + lp2 * w2 + lp3 * w3);
    wts[0][tid] = w0 * inv; wts[1][tid] = w1 * inv;
    wts[2][tid] = w2 * inv; wts[3][tid] = w3 * inv;
  }
  __syncthreads();
#pragma unroll
  for (int pp = 0; pp < 4; ++pp) {
    int e = pp * 256 + tid;          // uint4 units of 8 bf16: 1024 total
    int q = e >> 4, d8 = (e & 15) * 8;
    float s[8] = {};
#pragma unroll
    for (int p = 0; p < 4; ++p) {
      if (p < np) {
        uint4 v = *(const uint4*)&pOb[(i0 + p) * 8192 + q * 128 + d8];
        float w = wts[p][q];
        s[0] += bf2f((unsigned short)(v.x & 0xffff)) * w;
        s[1] += bf2f((unsigned short)(v.x >> 16)) * w;
        s[2] += bf2f((unsigned short)(v.y & 0xffff)) * w;
        s[3] += bf2f((unsigned short)(v.y >> 16)) * w;
        s[4] += bf2f((unsigned short)(v.z & 0xffff)) * w;
        s[5] += bf2f((unsigned short)(v.z >> 16)) * w;
        s[6] += bf2f((unsigned short)(v.w & 0xffff)) * w;
        s[7] += bf2f((unsigned short)(v.w >> 16)) * w;
      }
    }
    long ob_ = ((long)b * SS + q0 + q) * 2048 + h * 128 + d8;
    ushort4 o0 = { f2bf(s[0]), f2bf(s[1]), f2bf(s[2]), f2bf(s[3]) };
    ushort4 o1 = { f2bf(s[4]), f2bf(s[5]), f2bf(s[6]), f2bf(s[7]) };
    *(ushort4*)&o[ob_] = o0;
    *(ushort4*)&o[ob_ + 4] = o1;
  }
}

extern "C" void kernel_launch(void* const* d_in, const int* in_sizes, int n_in,
                              void* d_out, int out_size, void* d_ws, size_t ws_size,
                              hipStream_t stream) {
  const float* x    = (const float*)d_in[0];
  const float* wqd  = (const float*)d_in[1];
  const float* bqd  = (const float*)d_in[2];
  const float* qnw  = (const float*)d_in[3];
  const float* wqu  = (const float*)d_in[4];
  const float* bqu  = (const float*)d_in[5];
  const float* wkvd = (const float*)d_in[6];
  const float* bkvd = (const float*)d_in[7];
  const float* kvnw = (const float*)d_in[8];
  const float* wkvu = (const float*)d_in[9];
  const float* bkvu = (const float*)d_in[10];
  const float* wout = (const float*)d_in[11];
  const float* bout = (const float*)d_in[12];
  float* out = (float*)d_out;

  char* ws = (char*)d_ws;
  size_t off = 0;
  auto alloc = [&](size_t sz) {
    char* p = ws + off;
    off += (sz + 255) & ~(size_t)255;
    return p;
  };
  unsigned short* xb    = (unsigned short*)alloc((size_t)NROWS * 2048 * 2);
  unsigned short* wqkt  = (unsigned short*)alloc((size_t)2176 * 2048 * 2);  // [wqd;wkvd]^T
  unsigned short* wqut  = (unsigned short*)alloc((size_t)3072 * 1536 * 2);
  unsigned short* wkvut = (unsigned short*)alloc((size_t)4096 * 512 * 2);
  unsigned short* woutt = (unsigned short*)alloc((size_t)2048 * 2048 * 2);
  unsigned short* qn    = (unsigned short*)alloc((size_t)NROWS * 1536 * 2);
  unsigned short* kvn   = (unsigned short*)alloc((size_t)NROWS * 512 * 2);
  unsigned short* qfb   = (unsigned short*)alloc((size_t)32 * SS * 192 * 2);
  unsigned short* kfb   = (unsigned short*)alloc((size_t)32 * SS * 192 * 2);   // kf3 tiled
  unsigned short* vtb   = (unsigned short*)alloc((size_t)32 * 128 * SS * 2);   // vt3 tiled
  unsigned short* ob    = (unsigned short*)alloc((size_t)NROWS * 2048 * 2);
  float*  mbias = (float*)alloc((size_t)2176 * 4);
  float2* rtab  = (float2*)alloc((size_t)SS * 32 * 8);
  unsigned short* pOb = (unsigned short*)alloc((size_t)2304 * 8192 * 2);   // 37.7 MB bf16 partials
  float*  pml   = (float*)alloc((size_t)2304 * 128 * 4);    // partial m/ls
  unsigned short* sCb = (unsigned short*)alloc((size_t)NROWS * 2176 * 2);  // merged qd|kvd (bf16)

  // fused preprocessing: convert + 5 transposes + bias merge + rope table
  k_prep<<<17417, 256, 0, stream>>>(x, xb, wqd, wqu, wkvd, wkvu, wout,
                                    wqkt, wqut, wkvut, woutt, bqd, bkvd, mbias, rtab);

  // down-projections (merged, bf16 out): sCb = x @ [wqd|wkvd] + bias
  k_gemm_c16<<<32 * 17, 256, 0, stream>>>(xb, wqkt, mbias, sCb, NROWS, 2176, 2048);

  // both rmsnorms in one launch
  k_rmsnorm2<<<2 * NROWS, 256, 0, stream>>>(sCb, qnw, kvnw, qn, kvn);

  // up-projections + krope in one launch
  k_up<<<2816, 256, 0, stream>>>(qn, wqut, bqu, kvn, wkvut, bkvu, sCb, rtab,
                                 qfb, kfb, vtb);

  // attention: deep split-KV (2560 blocks, max 9 iters) + merge
  k_attn<<<2560, 256, 0, stream>>>(qfb, kfb, vtb, ob, pOb, pml);
  k_merge<<<768, 256, 0, stream>>>(pOb, pml, ob);

  // output projection
  k_gemm<<<32 * 16, 256, 0, stream>>>(ob, woutt, bout, out, NROWS, 2048, 2048);
}